// Round 14
// baseline (359.703 us; speedup 1.0000x reference)
//
#include <hip/hip_runtime.h>
#include <hip/hip_bf16.h>

#define H 1024
#define SEQ 4096
#define BQ 64   // Kq
#define NB 16   // batch

typedef float f32x4 __attribute__((ext_vector_type(4)));
typedef __bf16 bf16x8 __attribute__((ext_vector_type(8)));

__device__ __forceinline__ void split_bf16(const float* x, bf16x8& hi, bf16x8& lo)
{
    #pragma unroll
    for (int i = 0; i < 8; ++i) {
        float v = x[i];
        __bf16 h = (__bf16)v;
        hi[i] = h;
        lo[i] = (__bf16)(v - (float)h);
    }
}

__device__ __forceinline__ void gload_lds16(const float* g, void* lds)
{
    __builtin_amdgcn_global_load_lds(
        (const __attribute__((address_space(1))) void*)g,
        (__attribute__((address_space(3))) void*)lds, 16, 0, 0);
}

// ---------------------------------------------------------------------------
// 512-thread split-K(x2)-in-block MFMA GEMM (BNK-true): C = A @ B^T*scale+bias
// CVEC: additionally cvec[m] += cscale * sum_n C[m][n]*bk[n] (atomic).
// ---------------------------------------------------------------------------
template<bool CVEC>
__global__ __launch_bounds__(512)
void gemm_bt_512(const float* __restrict__ A, const float* __restrict__ Bm,
                 const float* __restrict__ bias, float* __restrict__ C,
                 float scale, const float* __restrict__ bk,
                 float* __restrict__ cvec, float cscale)
{
    const int m0 = blockIdx.x * 64;
    const int n0 = blockIdx.y * 64;
    const int t   = threadIdx.x;
    const int w   = t >> 6;
    const int wm  = w & 3;      // m-subtile
    const int kh  = w >> 2;     // k-half
    const int l   = t & 63;
    const int row = l & 15;
    const int kg  = l >> 4;

    const float* ap = A + (size_t)(m0 + wm * 16 + row) * H + kh * 512 + kg * 8;
    const float* bp = Bm + (size_t)(n0 + row) * H + kh * 512 + kg * 8;

    f32x4 acc[4] = {};
    for (int k0 = 0; k0 < 512; k0 += 32) {
        float a8[8];
        *reinterpret_cast<float4*>(&a8[0]) = *reinterpret_cast<const float4*>(ap + k0);
        *reinterpret_cast<float4*>(&a8[4]) = *reinterpret_cast<const float4*>(ap + k0 + 4);
        bf16x8 ahi, alo;
        split_bf16(a8, ahi, alo);
        #pragma unroll
        for (int j = 0; j < 4; ++j) {
            float b8[8];
            const float* bjp = bp + (size_t)j * 16 * H + k0;
            *reinterpret_cast<float4*>(&b8[0]) = *reinterpret_cast<const float4*>(bjp);
            *reinterpret_cast<float4*>(&b8[4]) = *reinterpret_cast<const float4*>(bjp + 4);
            bf16x8 bhi, blo;
            split_bf16(b8, bhi, blo);
            acc[j] = __builtin_amdgcn_mfma_f32_16x16x32_bf16(ahi, bhi, acc[j], 0, 0, 0);
            acc[j] = __builtin_amdgcn_mfma_f32_16x16x32_bf16(ahi, blo, acc[j], 0, 0, 0);
            acc[j] = __builtin_amdgcn_mfma_f32_16x16x32_bf16(alo, bhi, acc[j], 0, 0, 0);
        }
    }

    __shared__ f32x4 red[4][4][64];   // partials from kh==1 waves (16 KB)
    if (kh == 1) {
        #pragma unroll
        for (int j = 0; j < 4; ++j) red[wm][j][l] = acc[j];
    }
    __syncthreads();
    if (kh == 0) {
        float p[4] = {0.f, 0.f, 0.f, 0.f};
        #pragma unroll
        for (int j = 0; j < 4; ++j) {
            f32x4 s = acc[j] + red[wm][j][l];
            int n = n0 + j * 16 + row;
            float bb = bias ? bias[n] : 0.f;
            float bkv = CVEC ? bk[n] : 0.f;
            #pragma unroll
            for (int r = 0; r < 4; ++r) {
                int m = m0 + wm * 16 + kg * 4 + r;
                float o = s[r] * scale + bb;
                C[(size_t)m * H + n] = o;
                if (CVEC) p[r] += o * bkv;
            }
        }
        if (CVEC) {
            #pragma unroll
            for (int r = 0; r < 4; ++r) {
                #pragma unroll
                for (int off = 1; off < 16; off <<= 1)
                    p[r] += __shfl_xor(p[r], off);
            }
            if (row == 0) {
                #pragma unroll
                for (int r = 0; r < 4; ++r)
                    atomicAdd(&cvec[m0 + wm * 16 + kg * 4 + r], p[r] * cscale);
            }
        }
    }
}

// ---------------------------------------------------------------------------
// N-proj, B read strided directly from Wk[k][n]: N = (q @ Wk) * scale
// -> pre-split bf16 hi/lo [m][n]. 512-thr split-K(x2).
// ---------------------------------------------------------------------------
__global__ __launch_bounds__(512)
void ngemm_direct(const float* __restrict__ A, const float* __restrict__ Wk,
                  __bf16* __restrict__ Nhi, __bf16* __restrict__ Nlo, float scale)
{
    const int m0 = blockIdx.x * 64;
    const int n0 = blockIdx.y * 64;
    const int t   = threadIdx.x;
    const int w   = t >> 6;
    const int wm  = w & 3;
    const int kh  = w >> 2;
    const int l   = t & 63;
    const int row = l & 15;
    const int kg  = l >> 4;

    const float* ap = A + (size_t)(m0 + wm * 16 + row) * H + kh * 512 + kg * 8;
    const float* bp = Wk + (size_t)(kh * 512 + kg * 8) * H + n0 + row;

    f32x4 acc[4] = {};
    for (int k0 = 0; k0 < 512; k0 += 32) {
        float a8[8];
        *reinterpret_cast<float4*>(&a8[0]) = *reinterpret_cast<const float4*>(ap + k0);
        *reinterpret_cast<float4*>(&a8[4]) = *reinterpret_cast<const float4*>(ap + k0 + 4);
        bf16x8 ahi, alo;
        split_bf16(a8, ahi, alo);
        #pragma unroll
        for (int j = 0; j < 4; ++j) {
            float b8[8];
            #pragma unroll
            for (int e = 0; e < 8; ++e)
                b8[e] = bp[(size_t)(k0 + e) * H + j * 16];
            bf16x8 bhi, blo;
            split_bf16(b8, bhi, blo);
            acc[j] = __builtin_amdgcn_mfma_f32_16x16x32_bf16(ahi, bhi, acc[j], 0, 0, 0);
            acc[j] = __builtin_amdgcn_mfma_f32_16x16x32_bf16(ahi, blo, acc[j], 0, 0, 0);
            acc[j] = __builtin_amdgcn_mfma_f32_16x16x32_bf16(alo, bhi, acc[j], 0, 0, 0);
        }
    }

    __shared__ f32x4 red[4][4][64];
    if (kh == 1) {
        #pragma unroll
        for (int j = 0; j < 4; ++j) red[wm][j][l] = acc[j];
    }
    __syncthreads();
    if (kh == 0) {
        #pragma unroll
        for (int j = 0; j < 4; ++j) {
            f32x4 s = acc[j] + red[wm][j][l];
            int n = n0 + j * 16 + row;
            #pragma unroll
            for (int r = 0; r < 4; ++r) {
                int m = m0 + wm * 16 + kg * 4 + r;
                float v = s[r] * scale;
                __bf16 hi = (__bf16)v;
                Nhi[(size_t)m * H + n] = hi;
                Nlo[(size_t)m * H + n] = (__bf16)(v - (float)hi);
            }
        }
    }
}

// ---------------------------------------------------------------------------
// scores: D[qi][s] = N @ keys^T  (A = N bf16 hi/lo direct from L2;
// B = keys f32 staged via global_load_lds, source-swizzled slot = kb^(s&7),
// double-buffered; tmat-shaped loop). Block = 64 s x 64 qi, 256 thr.
// Fused per-64s-chunk softmax stats. Grid 1024, XCD swizzle.
// ---------------------------------------------------------------------------
__global__ __launch_bounds__(256)
void scores_mfma(const float* __restrict__ keys,
                 const __bf16* __restrict__ Nhi, const __bf16* __restrict__ Nlo,
                 const float* __restrict__ cvec, float* __restrict__ scores,
                 float* __restrict__ pmax, float* __restrict__ psum)
{
    const int id = blockIdx.x;          // 1024 blocks
    const int x  = id & 7;
    const int m  = id >> 3;             // 0..127
    const int b  = 2 * x + (m >> 6);    // 2 batches per XCD
    const int ch = m & 63;
    const int s0 = ch * 64;

    const int t   = threadIdx.x;
    const int w   = t >> 6;             // 0..3 : s-subtile
    const int l   = t & 63;
    const int cl  = l & 15;             // col lane: s-within-tile AND A-row qi
    const int kg  = l >> 4;

    __shared__ float klds[2][64][8][8]; // [buf][s][slot][e] f32, 16 KB each
    __shared__ float redm[4][64];

    const float* kb_ = keys + ((size_t)b * SEQ + s0) * H;
    const __bf16* nhb = Nhi + (size_t)b * BQ * H;
    const __bf16* nlb = Nlo + (size_t)b * BQ * H;

    // stage 64s x 64k chunk at kc into klds[buf]; dest linear, source swizzled
    #define KSTAGE(buf, kc)                                                    \
    {                                                                          \
        _Pragma("unroll")                                                      \
        for (int rd = 0; rd < 4; ++rd) {                                       \
            int d  = rd * 1024 + w * 256 + l * 4;                              \
            int ss = d >> 6;                                                   \
            int sl = (d >> 3) & 7;                                             \
            int e0 = d & 7;                                                    \
            const float* src = kb_ + (size_t)ss * H + (kc) +                   \
                               ((sl ^ (ss & 7)) << 3) + e0;                    \
            gload_lds16(src, (void*)(&klds[buf][0][0][0] + rd * 1024 + w * 256)); \
        }                                                                      \
    }

    f32x4 acc[4] = {};
    KSTAGE(0, 0);
    __syncthreads();

    for (int c = 0; c < 16; ++c) {
        const int buf = c & 1;
        if (c < 15) KSTAGE(buf ^ 1, (c + 1) * 64);
        const int kc = c * 64;
        #pragma unroll
        for (int ii = 0; ii < 2; ++ii) {
            // B-fragment (keys^T): lane (col=s, kgrp) reads 8 k-floats
            const int srow = w * 16 + cl;
            const int slot = (ii * 4 + kg) ^ (srow & 7);
            float b8[8];
            *reinterpret_cast<float4*>(&b8[0]) =
                *reinterpret_cast<const float4*>(&klds[buf][srow][slot][0]);
            *reinterpret_cast<float4*>(&b8[4]) =
                *reinterpret_cast<const float4*>(&klds[buf][srow][slot][4]);
            bf16x8 bhi, blo;
            split_bf16(b8, bhi, blo);
            #pragma unroll
            for (int j = 0; j < 4; ++j) {
                // A-fragment (N): row qi = j*16+cl, k contiguous
                size_t ao = (size_t)(j * 16 + cl) * H + kc + ii * 32 + kg * 8;
                bf16x8 ahi = *reinterpret_cast<const bf16x8*>(nhb + ao);
                bf16x8 alo = *reinterpret_cast<const bf16x8*>(nlb + ao);
                acc[j] = __builtin_amdgcn_mfma_f32_16x16x32_bf16(ahi, bhi, acc[j], 0, 0, 0);
                acc[j] = __builtin_amdgcn_mfma_f32_16x16x32_bf16(ahi, blo, acc[j], 0, 0, 0);
                acc[j] = __builtin_amdgcn_mfma_f32_16x16x32_bf16(alo, bhi, acc[j], 0, 0, 0);
            }
        }
        __syncthreads();
    }
    #undef KSTAGE

    // D: col(cl)=s-within-tile, row = j*16 + kg*4 + r = qi
    const int s = s0 + w * 16 + cl;
    f32x4 cvr[4];
    #pragma unroll
    for (int j = 0; j < 4; ++j)
        cvr[j] = *reinterpret_cast<const f32x4*>(&cvec[b * BQ + j * 16 + kg * 4]);
    #pragma unroll
    for (int j = 0; j < 4; ++j) {
        #pragma unroll
        for (int r = 0; r < 4; ++r) {
            float v = acc[j][r] + cvr[j][r];
            acc[j][r] = v;
            scores[((size_t)b * SEQ + s) * BQ + j * 16 + kg * 4 + r] = v;
        }
    }
    // fused stats: per-qi max/sum over this block's 64 s rows
    f32x4 mm[4];
    #pragma unroll
    for (int j = 0; j < 4; ++j) {
        mm[j] = acc[j];
        #pragma unroll
        for (int off = 1; off < 16; off <<= 1) {
            #pragma unroll
            for (int r = 0; r < 4; ++r)
                mm[j][r] = fmaxf(mm[j][r], __shfl_xor(mm[j][r], off));
        }
    }
    if (cl == 0) {
        #pragma unroll
        for (int j = 0; j < 4; ++j)
            *reinterpret_cast<f32x4*>(&redm[w][j * 16 + kg * 4]) = mm[j];
    }
    __syncthreads();
    f32x4 Mj[4];
    #pragma unroll
    for (int j = 0; j < 4; ++j) {
        f32x4 M = *reinterpret_cast<const f32x4*>(&redm[0][j * 16 + kg * 4]);
        #pragma unroll
        for (int ww = 1; ww < 4; ++ww) {
            f32x4 o = *reinterpret_cast<const f32x4*>(&redm[ww][j * 16 + kg * 4]);
            #pragma unroll
            for (int r = 0; r < 4; ++r) M[r] = fmaxf(M[r], o[r]);
        }
        Mj[j] = M;
    }
    __syncthreads();
    f32x4 se[4];
    #pragma unroll
    for (int j = 0; j < 4; ++j) {
        #pragma unroll
        for (int r = 0; r < 4; ++r) se[j][r] = __expf(acc[j][r] - Mj[j][r]);
        #pragma unroll
        for (int off = 1; off < 16; off <<= 1) {
            #pragma unroll
            for (int r = 0; r < 4; ++r)
                se[j][r] += __shfl_xor(se[j][r], off);
        }
    }
    if (cl == 0) {
        #pragma unroll
        for (int j = 0; j < 4; ++j)
            *reinterpret_cast<f32x4*>(&redm[w][j * 16 + kg * 4]) = se[j];
    }
    __syncthreads();
    if (w == 0 && cl == 0) {
        #pragma unroll
        for (int j = 0; j < 4; ++j) {
            f32x4 ssum = *reinterpret_cast<const f32x4*>(&redm[0][j * 16 + kg * 4]);
            #pragma unroll
            for (int ww = 1; ww < 4; ++ww) {
                f32x4 o = *reinterpret_cast<const f32x4*>(&redm[ww][j * 16 + kg * 4]);
                #pragma unroll
                for (int r = 0; r < 4; ++r) ssum[r] += o[r];
            }
            *reinterpret_cast<f32x4*>(&pmax[((size_t)b * 64 + ch) * 64 + j * 16 + kg * 4]) = Mj[j];
            *reinterpret_cast<f32x4*>(&psum[((size_t)b * 64 + ch) * 64 + j * 16 + kg * 4]) = ssum;
        }
    }
}

// ---------------------------------------------------------------------------
// normalize in place (inline global-stat combine over 64 chunks) + bf16 copy
// ---------------------------------------------------------------------------
__global__ __launch_bounds__(256)
void sm_norm(float* __restrict__ attn, const float* __restrict__ pmax,
             const float* __restrict__ psum, __hip_bfloat16* __restrict__ abfT)
{
    __shared__ float tile[64][133];
    const int b  = blockIdx.y;
    const int ch = blockIdx.x;
    const int t  = threadIdx.x;
    const int qi = t & 63;
    const int g  = t >> 6;

    float M = -1e30f;
    #pragma unroll 4
    for (int c = 0; c < 64; ++c)
        M = fmaxf(M, pmax[((size_t)b * 64 + c) * 64 + qi]);
    float ssum = 0.f;
    #pragma unroll 4
    for (int c = 0; c < 64; ++c)
        ssum += psum[((size_t)b * 64 + c) * 64 + qi] *
                __expf(pmax[((size_t)b * 64 + c) * 64 + qi] - M);
    const float inv = 1.f / ssum;

    float* sb = attn + ((size_t)b * SEQ + ch * 128) * BQ;
    #pragma unroll 8
    for (int i = 0; i < 32; ++i) {
        int sl = g + i * 4;
        size_t idx = (size_t)sl * BQ + qi;
        float w = __expf(sb[idx] - M) * inv;
        sb[idx] = w;
        tile[qi][sl] = w;
    }
    __syncthreads();
    const int qo = t >> 2;
    const int c  = (t & 3) * 32;
    __hip_bfloat16* dst = abfT + ((size_t)(b * BQ + qo)) * SEQ + ch * 128 + c;
    #pragma unroll
    for (int v = 0; v < 4; ++v) {
        bf16x8 w8;
        #pragma unroll
        for (int e = 0; e < 8; ++e)
            w8[e] = (__bf16)tile[qo][c + v * 8 + e];
        *reinterpret_cast<bf16x8*>(dst + v * 8) = w8;
    }
}

// ---------------------------------------------------------------------------
// Tpart[sc][b][qi][h] = sum_{s in chunk} abfT[b,qi,s] * values[b,s,h]
// values staged via global_load_lds (dbuf, pre-swizzled source col).
// ---------------------------------------------------------------------------
template<int SC>
__global__ __launch_bounds__(256)
void tmat_mfma(const __hip_bfloat16* __restrict__ abfT,
               const float* __restrict__ values,
               float* __restrict__ Tpart)
{
    const int i  = blockIdx.x;
    const int h0 = ((i >> 3) & 7) * 128;
    const int g  = (i & 7) + 8 * (i >> 6);
    const int b  = g / SC;
    const int sc = g % SC;
    const int schunk = SEQ / SC;

    const int w   = threadIdx.x >> 6;
    const int l   = threadIdx.x & 63;
    const int row = l & 15;
    const int kg  = l >> 4;
    const int sbase = sc * schunk;

    __shared__ float vlds[2][32][128];   // 32 KB

    const __hip_bfloat16* ap = abfT + ((size_t)b * BQ + row) * SEQ + sbase + kg * 8;
    const float* vb = values + ((size_t)b * SEQ + sbase) * H + h0;

    const int nk = schunk / 32;

    #define STAGE(buf, k0)                                                     \
        {                                                                      \
            _Pragma("unroll")                                                  \
            for (int ii = 0; ii < 4; ++ii) {                                   \
                int elem = w * 1024 + ii * 256 + l * 4;                        \
                int k    = elem >> 7;                                          \
                int cc   = elem & 127;                                         \
                int csw  = cc ^ ((k >> 3) << 4);                               \
                const float* src = vb + (size_t)((k0) + k) * H + csw;          \
                gload_lds16(src, (void*)(&vlds[buf][0][0] + w * 1024 + ii * 256)); \
            }                                                                  \
        }

    f32x4 acc[4][2] = {};
    STAGE(0, 0);
    __syncthreads();

    for (int ks = 0; ks < nk; ++ks) {
        const int buf = ks & 1;
        if (ks + 1 < nk) STAGE(buf ^ 1, (ks + 1) * 32);
        const int k0 = ks * 32;
        bf16x8 a[4];
        #pragma unroll
        for (int q = 0; q < 4; ++q)
            a[q] = *reinterpret_cast<const bf16x8*>(ap + (size_t)q * 16 * SEQ + k0);
        #pragma unroll
        for (int j = 0; j < 2; ++j) {
            const int col = (w * 32 + j * 16 + row) ^ (kg << 4);
            float b8[8];
            #pragma unroll
            for (int e = 0; e < 8; ++e)
                b8[e] = vlds[buf][kg * 8 + e][col];
            bf16x8 bhi, blo;
            split_bf16(b8, bhi, blo);
            #pragma unroll
            for (int q = 0; q < 4; ++q) {
                acc[q][j] = __builtin_amdgcn_mfma_f32_16x16x32_bf16(a[q], bhi, acc[q][j], 0, 0, 0);
                acc[q][j] = __builtin_amdgcn_mfma_f32_16x16x32_bf16(a[q], blo, acc[q][j], 0, 0, 0);
            }
        }
        __syncthreads();
    }
    #undef STAGE

    float* tp = Tpart + ((size_t)sc * NB + b) * BQ * H;
    #pragma unroll
    for (int q = 0; q < 4; ++q) {
        #pragma unroll
        for (int j = 0; j < 2; ++j) {
            int h = h0 + w * 32 + j * 16 + row;
            #pragma unroll
            for (int r = 0; r < 4; ++r) {
                int qi = q * 16 + kg * 4 + r;
                tp[(size_t)qi * H + h] = acc[q][j][r];
            }
        }
    }
}

// ---------------------------------------------------------------------------
// In-place partial reduction: Tpart[0][i] = sum_p Tpart[p][i]
// ---------------------------------------------------------------------------
template<int SC>
__global__ __launch_bounds__(256)
void tsum_kernel(float* __restrict__ Tpart)
{
    const size_t stride = (size_t)NB * BQ * H;
    size_t i = ((size_t)blockIdx.x * 256 + threadIdx.x) * 4;
    f32x4 s = *reinterpret_cast<const f32x4*>(Tpart + i);
    #pragma unroll
    for (int p = 1; p < SC; ++p)
        s += *reinterpret_cast<const f32x4*>(Tpart + p * stride + i);
    *reinterpret_cast<f32x4*>(Tpart + i) = s;
}

// ---------------------------------------------------------------------------
extern "C" void kernel_launch(void* const* d_in, const int* in_sizes, int n_in,
                              void* d_out, int out_size, void* d_ws, size_t ws_size,
                              hipStream_t stream)
{
    const float* queries = (const float*)d_in[0];
    const float* keys    = (const float*)d_in[1];
    const float* values  = (const float*)d_in[2];
    const float* Wq = (const float*)d_in[3];
    const float* bq = (const float*)d_in[4];
    const float* Wk = (const float*)d_in[5];
    const float* bk = (const float*)d_in[6];
    const float* Wv = (const float*)d_in[7];
    const float* bv = (const float*)d_in[8];

    float* out     = (float*)d_out;
    float* context = out;                          // 16*64*1024 f32
    float* attn    = out + (size_t)NB * BQ * H;    // 16*4096*64 f32

    const int SC = (ws_size >= (41ull << 20)) ? 8 : 2;

    char* ws = (char*)d_ws;
    float* q     = (float*)ws;                              // 4 MB  [0,4)
    __bf16* Nhi  = (__bf16*)(ws + (8ull << 20));            // 2 MB  [8,10)
    __bf16* Nlo  = (__bf16*)(ws + (10ull << 20));           // 2 MB  [10,12)
    float* Tpart = (float*)ws;                              // SC*4 MB (overlaps q/N, dead by tmat)
    __hip_bfloat16* abfT = (__hip_bfloat16*)(ws + (size_t)SC * (4ull << 20)); // 8 MB
    char* smalls = ws + (size_t)SC * (4ull << 20) + (8ull << 20);
    float* cvec  = (float*)smalls;                          // 4 KB
    float* pmax  = (float*)(smalls + (128u << 10));         // 256 KB
    float* psum  = (float*)(smalls + (512u << 10));         // 256 KB

    const float scale = 0.03125f; // 1/sqrt(1024)

    // cvec accumulated atomically in q-GEMM epilogue
    hipMemsetAsync(cvec, 0, (size_t)NB * BQ * sizeof(float), stream);
    // q = queries @ Wq^T + bq  (+ cvec = scale*(q . bk))
    gemm_bt_512<true><<<dim3(16, 16), 512, 0, stream>>>(
        queries, Wq, bq, q, 1.0f, bk, cvec, scale);
    // N = (q @ Wk) * scale -> pre-split bf16 hi/lo
    ngemm_direct<<<dim3(16, 16), 512, 0, stream>>>(q, Wk, Nhi, Nlo, scale);
    // scores (A=N direct, B=keys gload_lds-staged) + fused softmax stats
    scores_mfma<<<1024, 256, 0, stream>>>(keys, Nhi, Nlo, cvec, attn, pmax, psum);
    // normalize (inline stat combine) + bf16 transposed copy
    sm_norm<<<dim3(32, NB), 256, 0, stream>>>(attn, pmax, psum, abfT);
    // T partials = attn^T @ values
    if (SC == 8) tmat_mfma<8><<<8 * NB * 8, 256, 0, stream>>>(abfT, values, Tpart);
    else         tmat_mfma<2><<<8 * NB * 2, 256, 0, stream>>>(abfT, values, Tpart);
    // Tsum (in place into partial 0)
    if (SC == 8) tsum_kernel<8><<<1024, 256, 0, stream>>>(Tpart);
    else         tsum_kernel<2><<<1024, 256, 0, stream>>>(Tpart);
    // context = Tsum @ Wv^T + bv
    gemm_bt_512<false><<<dim3(16, 16), 512, 0, stream>>>(
        Tpart, Wv, bv, context, 1.0f, nullptr, nullptr, 0.f);
}

// Round 15
// 299.089 us; speedup vs baseline: 1.2027x; 1.2027x over previous
//
#include <hip/hip_runtime.h>
#include <hip/hip_bf16.h>

#define H 1024
#define SEQ 4096
#define BQ 64   // Kq
#define NB 16   // batch

typedef float f32x4 __attribute__((ext_vector_type(4)));
typedef __bf16 bf16x8 __attribute__((ext_vector_type(8)));

__device__ __forceinline__ void split_bf16(const float* x, bf16x8& hi, bf16x8& lo)
{
    #pragma unroll
    for (int i = 0; i < 8; ++i) {
        float v = x[i];
        __bf16 h = (__bf16)v;
        hi[i] = h;
        lo[i] = (__bf16)(v - (float)h);
    }
}

__device__ __forceinline__ void cvt_bf16(const float* x, bf16x8& hi)
{
    #pragma unroll
    for (int i = 0; i < 8; ++i) hi[i] = (__bf16)x[i];
}

__device__ __forceinline__ void gload_lds16(const float* g, void* lds)
{
    __builtin_amdgcn_global_load_lds(
        (const __attribute__((address_space(1))) void*)g,
        (__attribute__((address_space(3))) void*)lds, 16, 0, 0);
}

// ---------------------------------------------------------------------------
// 512-thread split-K(x2)-in-block MFMA GEMM (BNK-true): C = A @ B^T*scale+bias
// CVEC: additionally cvec[m] += cscale * sum_n C[m][n]*bk[n] (atomic).
// NOUT: emit bf16 hi/lo (Nhi/Nlo) instead of f32 C.
// ---------------------------------------------------------------------------
template<bool CVEC, bool NOUT>
__global__ __launch_bounds__(512)
void gemm_bt_512(const float* __restrict__ A, const float* __restrict__ Bm,
                 const float* __restrict__ bias, float* __restrict__ C,
                 float scale, const float* __restrict__ bk,
                 float* __restrict__ cvec, float cscale,
                 __bf16* __restrict__ Nhi, __bf16* __restrict__ Nlo)
{
    const int m0 = blockIdx.x * 64;
    const int n0 = blockIdx.y * 64;
    const int t   = threadIdx.x;
    const int w   = t >> 6;
    const int wm  = w & 3;      // m-subtile
    const int kh  = w >> 2;     // k-half
    const int l   = t & 63;
    const int row = l & 15;
    const int kg  = l >> 4;

    const float* ap = A + (size_t)(m0 + wm * 16 + row) * H + kh * 512 + kg * 8;
    const float* bp = Bm + (size_t)(n0 + row) * H + kh * 512 + kg * 8;

    f32x4 acc[4] = {};
    for (int k0 = 0; k0 < 512; k0 += 32) {
        float a8[8];
        *reinterpret_cast<float4*>(&a8[0]) = *reinterpret_cast<const float4*>(ap + k0);
        *reinterpret_cast<float4*>(&a8[4]) = *reinterpret_cast<const float4*>(ap + k0 + 4);
        bf16x8 ahi, alo;
        split_bf16(a8, ahi, alo);
        #pragma unroll
        for (int j = 0; j < 4; ++j) {
            float b8[8];
            const float* bjp = bp + (size_t)j * 16 * H + k0;
            *reinterpret_cast<float4*>(&b8[0]) = *reinterpret_cast<const float4*>(bjp);
            *reinterpret_cast<float4*>(&b8[4]) = *reinterpret_cast<const float4*>(bjp + 4);
            bf16x8 bhi, blo;
            split_bf16(b8, bhi, blo);
            acc[j] = __builtin_amdgcn_mfma_f32_16x16x32_bf16(ahi, bhi, acc[j], 0, 0, 0);
            acc[j] = __builtin_amdgcn_mfma_f32_16x16x32_bf16(ahi, blo, acc[j], 0, 0, 0);
            acc[j] = __builtin_amdgcn_mfma_f32_16x16x32_bf16(alo, bhi, acc[j], 0, 0, 0);
        }
    }

    __shared__ f32x4 red[4][4][64];   // partials from kh==1 waves (16 KB)
    if (kh == 1) {
        #pragma unroll
        for (int j = 0; j < 4; ++j) red[wm][j][l] = acc[j];
    }
    __syncthreads();
    if (kh == 0) {
        float p[4] = {0.f, 0.f, 0.f, 0.f};
        #pragma unroll
        for (int j = 0; j < 4; ++j) {
            f32x4 s = acc[j] + red[wm][j][l];
            int n = n0 + j * 16 + row;
            float bb = (!NOUT && bias) ? bias[n] : 0.f;
            float bkv = CVEC ? bk[n] : 0.f;
            #pragma unroll
            for (int r = 0; r < 4; ++r) {
                int m = m0 + wm * 16 + kg * 4 + r;
                float o = s[r] * scale + bb;
                if (NOUT) {
                    __bf16 hi = (__bf16)o;
                    Nhi[(size_t)m * H + n] = hi;
                    Nlo[(size_t)m * H + n] = (__bf16)(o - (float)hi);
                } else {
                    C[(size_t)m * H + n] = o;
                }
                if (CVEC) p[r] += o * bkv;
            }
        }
        if (CVEC) {
            #pragma unroll
            for (int r = 0; r < 4; ++r) {
                #pragma unroll
                for (int off = 1; off < 16; off <<= 1)
                    p[r] += __shfl_xor(p[r], off);
            }
            if (row == 0) {
                #pragma unroll
                for (int r = 0; r < 4; ++r)
                    atomicAdd(&cvec[m0 + wm * 16 + kg * 4 + r], p[r] * cscale);
            }
        }
    }
}

// ---------------------------------------------------------------------------
// Wk transpose: WkT[n][k] = Wk[k][n]
// ---------------------------------------------------------------------------
__global__ __launch_bounds__(256)
void transpose_k(const float* __restrict__ Wk, float* __restrict__ WkT)
{
    __shared__ float tile[64][65];
    const int k0 = blockIdx.x * 64;
    const int n0 = blockIdx.y * 64;
    const int t  = threadIdx.x;
    const int c4 = (t & 15) * 4;
    const int r  = t >> 4;
    #pragma unroll
    for (int p = 0; p < 4; ++p) {
        float4 v = *reinterpret_cast<const float4*>(&Wk[(size_t)(k0 + r + 16 * p) * H + n0 + c4]);
        tile[r + 16 * p][c4 + 0] = v.x;
        tile[r + 16 * p][c4 + 1] = v.y;
        tile[r + 16 * p][c4 + 2] = v.z;
        tile[r + 16 * p][c4 + 3] = v.w;
    }
    __syncthreads();
    #pragma unroll
    for (int p = 0; p < 4; ++p) {
        int rr = r + 16 * p;
        float4 o;
        o.x = tile[c4 + 0][rr];
        o.y = tile[c4 + 1][rr];
        o.z = tile[c4 + 2][rr];
        o.w = tile[c4 + 3][rr];
        *reinterpret_cast<float4*>(&WkT[(size_t)(n0 + rr) * H + k0 + c4]) = o;
    }
}

// ---------------------------------------------------------------------------
// scores[b,s,qi] = sum_h keys[b,s,h]*N[b,qi,h] + c[b,qi]
// R13 structure: 64-k chunks, dbuf XOR-swizzled N LDS, 1 barrier/chunk,
// prefetch issued after barrier. KEYS BF16-HI ONLY (2 MFMAs; keys-lo term
// dropped — error ~2e-3 on scores, ~2e-4 on weights, well under threshold).
// Fused per-128-row-chunk softmax stats. 512 blocks x 512 thr, XCD swizzle.
// ---------------------------------------------------------------------------
__global__ __launch_bounds__(512, 4)
void scores_mfma(const float* __restrict__ keys,
                 const __bf16* __restrict__ Nhi, const __bf16* __restrict__ Nlo,
                 const float* __restrict__ cvec, float* __restrict__ scores,
                 float* __restrict__ pmax, float* __restrict__ psum)
{
    const int id = blockIdx.x;          // 512 blocks
    const int x  = id & 7;
    const int m  = id >> 3;             // 0..63
    const int b  = 2 * x + (m >> 5);    // 2 batches per XCD
    const int ch = m & 31;
    const int s0 = ch * 128;

    const int t   = threadIdx.x;
    const int w   = t >> 6;             // 0..7
    const int l   = t & 63;
    const int row = l & 15;
    const int kg  = l >> 4;

    __shared__ __bf16 nshH[2][64][8][8];  // [buf][qi][slot][e] (16 KB)
    __shared__ __bf16 nshL[2][64][8][8];  // 16 KB
    __shared__ float redm[8][64];         // 2 KB

    const float* ka = keys + ((size_t)b * SEQ + s0 + w * 16 + row) * H + kg * 8;
    const __bf16* nhb = Nhi + (size_t)b * BQ * H;
    const __bf16* nlb = Nlo + (size_t)b * BQ * H;

    // staging: thread t covers (qi = t>>3, kb = t&7) of the 64x64 chunk
    const int sqi = t >> 3;
    const int skb = t & 7;
    const int ssl = skb ^ (sqi & 7);

    // prologue: chunk 0 into reg set 0
    float4 kr[2][4];
    bf16x8 nh[2], nl[2];
    #pragma unroll
    for (int ii = 0; ii < 2; ++ii) {
        kr[0][2 * ii + 0] = *reinterpret_cast<const float4*>(ka + ii * 32);
        kr[0][2 * ii + 1] = *reinterpret_cast<const float4*>(ka + ii * 32 + 4);
    }
    {
        size_t go = (size_t)sqi * H + skb * 8;
        nh[0] = *reinterpret_cast<const bf16x8*>(nhb + go);
        nl[0] = *reinterpret_cast<const bf16x8*>(nlb + go);
    }

    f32x4 acc[4] = {};
    #pragma unroll
    for (int c = 0; c < 16; ++c) {
        const int buf = c & 1;
        // write N(c) regs -> LDS[buf] (waits vmcnt for those loads)
        *reinterpret_cast<bf16x8*>(&nshH[buf][sqi][ssl][0]) = nh[buf];
        *reinterpret_cast<bf16x8*>(&nshL[buf][sqi][ssl][0]) = nl[buf];
        __syncthreads();
        // issue chunk c+1 loads AFTER the barrier -> in flight during compute
        if (c < 15) {
            const int kc = (c + 1) * 64;
            #pragma unroll
            for (int ii = 0; ii < 2; ++ii) {
                kr[buf ^ 1][2 * ii + 0] = *reinterpret_cast<const float4*>(ka + kc + ii * 32);
                kr[buf ^ 1][2 * ii + 1] = *reinterpret_cast<const float4*>(ka + kc + ii * 32 + 4);
            }
            size_t go = (size_t)sqi * H + kc + skb * 8;
            nh[buf ^ 1] = *reinterpret_cast<const bf16x8*>(nhb + go);
            nl[buf ^ 1] = *reinterpret_cast<const bf16x8*>(nlb + go);
        }
        // compute chunk c from kr[buf] + LDS[buf]  (keys hi only)
        #pragma unroll
        for (int ii = 0; ii < 2; ++ii) {
            float a8[8];
            *reinterpret_cast<float4*>(&a8[0]) = kr[buf][2 * ii + 0];
            *reinterpret_cast<float4*>(&a8[4]) = kr[buf][2 * ii + 1];
            bf16x8 ahi;
            cvt_bf16(a8, ahi);
            const int kb = ii * 4 + kg;
            const int slot = kb ^ (row & 7);
            #pragma unroll
            for (int j = 0; j < 4; ++j) {
                const int qi = j * 16 + row;
                bf16x8 bhi = *reinterpret_cast<const bf16x8*>(&nshH[buf][qi][slot][0]);
                bf16x8 blo = *reinterpret_cast<const bf16x8*>(&nshL[buf][qi][slot][0]);
                acc[j] = __builtin_amdgcn_mfma_f32_16x16x32_bf16(ahi, bhi, acc[j], 0, 0, 0);
                acc[j] = __builtin_amdgcn_mfma_f32_16x16x32_bf16(ahi, blo, acc[j], 0, 0, 0);
            }
        }
    }

    // epilogue: add cvec, write scores
    #pragma unroll
    for (int j = 0; j < 4; ++j) {
        int qi = j * 16 + row;
        float cv = cvec[b * BQ + qi];
        #pragma unroll
        for (int r = 0; r < 4; ++r) {
            acc[j][r] += cv;
            int s = s0 + w * 16 + kg * 4 + r;
            scores[((size_t)b * SEQ + s) * BQ + qi] = acc[j][r];
        }
    }
    // fused partial stats over this block's 128 s-rows
    float mj[4];
    #pragma unroll
    for (int j = 0; j < 4; ++j) {
        float mm = fmaxf(fmaxf(acc[j][0], acc[j][1]), fmaxf(acc[j][2], acc[j][3]));
        mm = fmaxf(mm, __shfl_xor(mm, 16));
        mm = fmaxf(mm, __shfl_xor(mm, 32));
        mj[j] = mm;
    }
    __syncthreads();
    if (kg == 0) {
        #pragma unroll
        for (int j = 0; j < 4; ++j) redm[w][j * 16 + row] = mj[j];
    }
    __syncthreads();
    float Mj[4];
    #pragma unroll
    for (int j = 0; j < 4; ++j) {
        const int qi = j * 16 + row;
        float M = redm[0][qi];
        #pragma unroll
        for (int ww = 1; ww < 8; ++ww) M = fmaxf(M, redm[ww][qi]);
        Mj[j] = M;
    }
    float sj[4];
    #pragma unroll
    for (int j = 0; j < 4; ++j) {
        float s = 0.f;
        #pragma unroll
        for (int r = 0; r < 4; ++r) s += __expf(acc[j][r] - Mj[j]);
        s += __shfl_xor(s, 16);
        s += __shfl_xor(s, 32);
        sj[j] = s;
    }
    __syncthreads();
    if (kg == 0) {
        #pragma unroll
        for (int j = 0; j < 4; ++j) redm[w][j * 16 + row] = sj[j];
    }
    __syncthreads();
    if (w == 0 && kg == 0) {
        #pragma unroll
        for (int j = 0; j < 4; ++j) {
            const int qi = j * 16 + row;
            float ss = 0.f;
            #pragma unroll
            for (int ww = 0; ww < 8; ++ww) ss += redm[ww][qi];
            pmax[((size_t)b * 32 + ch) * 64 + qi] = Mj[j];
            psum[((size_t)b * 32 + ch) * 64 + qi] = ss;
        }
    }
}

// ---------------------------------------------------------------------------
// normalize in place (inline global-stat combine over 32 chunks) + bf16 copy
// ---------------------------------------------------------------------------
__global__ __launch_bounds__(256)
void sm_norm(float* __restrict__ attn, const float* __restrict__ pmax,
             const float* __restrict__ psum, __hip_bfloat16* __restrict__ abfT)
{
    __shared__ float tile[64][133];
    const int b  = blockIdx.y;
    const int ch = blockIdx.x;
    const int t  = threadIdx.x;
    const int qi = t & 63;
    const int g  = t >> 6;

    float M = -1e30f;
    #pragma unroll 4
    for (int c = 0; c < 32; ++c)
        M = fmaxf(M, pmax[((size_t)b * 32 + c) * 64 + qi]);
    float ssum = 0.f;
    #pragma unroll 4
    for (int c = 0; c < 32; ++c)
        ssum += psum[((size_t)b * 32 + c) * 64 + qi] *
                __expf(pmax[((size_t)b * 32 + c) * 64 + qi] - M);
    const float inv = 1.f / ssum;

    float* sb = attn + ((size_t)b * SEQ + ch * 128) * BQ;
    #pragma unroll 8
    for (int i = 0; i < 32; ++i) {
        int sl = g + i * 4;
        size_t idx = (size_t)sl * BQ + qi;
        float w = __expf(sb[idx] - M) * inv;
        sb[idx] = w;
        tile[qi][sl] = w;
    }
    __syncthreads();
    const int qo = t >> 2;
    const int c  = (t & 3) * 32;
    __hip_bfloat16* dst = abfT + ((size_t)(b * BQ + qo)) * SEQ + ch * 128 + c;
    #pragma unroll
    for (int v = 0; v < 4; ++v) {
        bf16x8 w8;
        #pragma unroll
        for (int e = 0; e < 8; ++e)
            w8[e] = (__bf16)tile[qo][c + v * 8 + e];
        *reinterpret_cast<bf16x8*>(dst + v * 8) = w8;
    }
}

// ---------------------------------------------------------------------------
// Tpart[sc][b][qi][h] = sum_{s in chunk} abfT[b,qi,s] * values[b,s,h]
// values staged via global_load_lds (dbuf, pre-swizzled source col).
// ---------------------------------------------------------------------------
template<int SC>
__global__ __launch_bounds__(256)
void tmat_mfma(const __hip_bfloat16* __restrict__ abfT,
               const float* __restrict__ values,
               float* __restrict__ Tpart)
{
    const int i  = blockIdx.x;
    const int h0 = ((i >> 3) & 7) * 128;
    const int g  = (i & 7) + 8 * (i >> 6);
    const int b  = g / SC;
    const int sc = g % SC;
    const int schunk = SEQ / SC;

    const int w   = threadIdx.x >> 6;
    const int l   = threadIdx.x & 63;
    const int row = l & 15;
    const int kg  = l >> 4;
    const int sbase = sc * schunk;

    __shared__ float vlds[2][32][128];   // 32 KB

    const __hip_bfloat16* ap = abfT + ((size_t)b * BQ + row) * SEQ + sbase + kg * 8;
    const float* vb = values + ((size_t)b * SEQ + sbase) * H + h0;

    const int nk = schunk / 32;

    #define STAGE(buf, k0)                                                     \
        {                                                                      \
            _Pragma("unroll")                                                  \
            for (int ii = 0; ii < 4; ++ii) {                                   \
                int elem = w * 1024 + ii * 256 + l * 4;                        \
                int k    = elem >> 7;                                          \
                int cc   = elem & 127;                                         \
                int csw  = cc ^ ((k >> 3) << 4);                               \
                const float* src = vb + (size_t)((k0) + k) * H + csw;          \
                gload_lds16(src, (void*)(&vlds[buf][0][0] + w * 1024 + ii * 256)); \
            }                                                                  \
        }

    f32x4 acc[4][2] = {};
    STAGE(0, 0);
    __syncthreads();

    for (int ks = 0; ks < nk; ++ks) {
        const int buf = ks & 1;
        if (ks + 1 < nk) STAGE(buf ^ 1, (ks + 1) * 32);
        const int k0 = ks * 32;
        bf16x8 a[4];
        #pragma unroll
        for (int q = 0; q < 4; ++q)
            a[q] = *reinterpret_cast<const bf16x8*>(ap + (size_t)q * 16 * SEQ + k0);
        #pragma unroll
        for (int j = 0; j < 2; ++j) {
            const int col = (w * 32 + j * 16 + row) ^ (kg << 4);
            float b8[8];
            #pragma unroll
            for (int e = 0; e < 8; ++e)
                b8[e] = vlds[buf][kg * 8 + e][col];
            bf16x8 bhi, blo;
            split_bf16(b8, bhi, blo);
            #pragma unroll
            for (int q = 0; q < 4; ++q) {
                acc[q][j] = __builtin_amdgcn_mfma_f32_16x16x32_bf16(a[q], bhi, acc[q][j], 0, 0, 0);
                acc[q][j] = __builtin_amdgcn_mfma_f32_16x16x32_bf16(a[q], blo, acc[q][j], 0, 0, 0);
            }
        }
        __syncthreads();
    }
    #undef STAGE

    float* tp = Tpart + ((size_t)sc * NB + b) * BQ * H;
    #pragma unroll
    for (int q = 0; q < 4; ++q) {
        #pragma unroll
        for (int j = 0; j < 2; ++j) {
            int h = h0 + w * 32 + j * 16 + row;
            #pragma unroll
            for (int r = 0; r < 4; ++r) {
                int qi = q * 16 + kg * 4 + r;
                tp[(size_t)qi * H + h] = acc[q][j][r];
            }
        }
    }
}

// ---------------------------------------------------------------------------
// In-place partial reduction: Tpart[0][i] = sum_p Tpart[p][i]
// ---------------------------------------------------------------------------
template<int SC>
__global__ __launch_bounds__(256)
void tsum_kernel(float* __restrict__ Tpart)
{
    const size_t stride = (size_t)NB * BQ * H;
    size_t i = ((size_t)blockIdx.x * 256 + threadIdx.x) * 4;
    f32x4 s = *reinterpret_cast<const f32x4*>(Tpart + i);
    #pragma unroll
    for (int p = 1; p < SC; ++p)
        s += *reinterpret_cast<const f32x4*>(Tpart + p * stride + i);
    *reinterpret_cast<f32x4*>(Tpart + i) = s;
}

// ---------------------------------------------------------------------------
extern "C" void kernel_launch(void* const* d_in, const int* in_sizes, int n_in,
                              void* d_out, int out_size, void* d_ws, size_t ws_size,
                              hipStream_t stream)
{
    const float* queries = (const float*)d_in[0];
    const float* keys    = (const float*)d_in[1];
    const float* values  = (const float*)d_in[2];
    const float* Wq = (const float*)d_in[3];
    const float* bq = (const float*)d_in[4];
    const float* Wk = (const float*)d_in[5];
    const float* bk = (const float*)d_in[6];
    const float* Wv = (const float*)d_in[7];
    const float* bv = (const float*)d_in[8];

    float* out     = (float*)d_out;
    float* context = out;                          // 16*64*1024 f32
    float* attn    = out + (size_t)NB * BQ * H;    // 16*4096*64 f32

    const int SC = (ws_size >= (41ull << 20)) ? 8 : 2;

    char* ws = (char*)d_ws;
    float* q     = (float*)ws;                              // 4 MB  [0,4)
    float* WkT   = (float*)(ws + (4ull << 20));             // 4 MB  [4,8)
    __bf16* Nhi  = (__bf16*)(ws + (8ull << 20));            // 2 MB  [8,10)
    __bf16* Nlo  = (__bf16*)(ws + (10ull << 20));           // 2 MB  [10,12)
    float* Tpart = (float*)ws;                              // SC*4 MB (overlaps q/WkT/N, dead by tmat)
    __hip_bfloat16* abfT = (__hip_bfloat16*)(ws + (size_t)SC * (4ull << 20)); // 8 MB
    char* smalls = ws + (size_t)SC * (4ull << 20) + (8ull << 20);
    float* cvec  = (float*)smalls;                          // 4 KB
    float* pmax  = (float*)(smalls + (128u << 10));         // 128 KB
    float* psum  = (float*)(smalls + (512u << 10));         // 128 KB

    const float scale = 0.03125f; // 1/sqrt(1024)

    // cvec accumulated atomically in q-GEMM epilogue
    hipMemsetAsync(cvec, 0, (size_t)NB * BQ * sizeof(float), stream);
    // WkT = Wk^T (contiguous B for the N-GEMM)
    transpose_k<<<dim3(16, 16), 256, 0, stream>>>(Wk, WkT);
    // q = queries @ Wq^T + bq  (+ cvec = scale*(q . bk))
    gemm_bt_512<true, false><<<dim3(16, 16), 512, 0, stream>>>(
        queries, Wq, bq, q, 1.0f, bk, cvec, scale, nullptr, nullptr);
    // N = (q @ Wk) * scale -> pre-split bf16 hi/lo  (BT layout via WkT)
    gemm_bt_512<false, true><<<dim3(16, 16), 512, 0, stream>>>(
        q, WkT, nullptr, nullptr, scale, nullptr, nullptr, 0.f, Nhi, Nlo);
    // scores + fused per-chunk softmax stats (keys bf16-hi only)
    scores_mfma<<<512, 512, 0, stream>>>(keys, Nhi, Nlo, cvec, attn, pmax, psum);
    // normalize (inline stat combine) + bf16 transposed copy
    sm_norm<<<dim3(32, NB), 256, 0, stream>>>(attn, pmax, psum, abfT);
    // T partials = attn^T @ values
    if (SC == 8) tmat_mfma<8><<<8 * NB * 8, 256, 0, stream>>>(abfT, values, Tpart);
    else         tmat_mfma<2><<<8 * NB * 2, 256, 0, stream>>>(abfT, values, Tpart);
    // Tsum (in place into partial 0)
    if (SC == 8) tsum_kernel<8><<<1024, 256, 0, stream>>>(Tpart);
    else         tsum_kernel<2><<<1024, 256, 0, stream>>>(Tpart);
    // context = Tsum @ Wv^T + bv
    gemm_bt_512<false, false><<<dim3(16, 16), 512, 0, stream>>>(
        Tpart, Wv, bv, context, 1.0f, nullptr, nullptr, 0.f, nullptr, nullptr);
}

// Round 16
// 282.217 us; speedup vs baseline: 1.2746x; 1.0598x over previous
//
#include <hip/hip_runtime.h>
#include <hip/hip_bf16.h>

#define H 1024
#define SEQ 4096
#define BQ 64   // Kq
#define NB 16   // batch

typedef float f32x4 __attribute__((ext_vector_type(4)));
typedef __bf16 bf16x8 __attribute__((ext_vector_type(8)));

__device__ __forceinline__ void split_bf16(const float* x, bf16x8& hi, bf16x8& lo)
{
    #pragma unroll
    for (int i = 0; i < 8; ++i) {
        float v = x[i];
        __bf16 h = (__bf16)v;
        hi[i] = h;
        lo[i] = (__bf16)(v - (float)h);
    }
}

__device__ __forceinline__ void gload_lds16(const float* g, void* lds)
{
    __builtin_amdgcn_global_load_lds(
        (const __attribute__((address_space(1))) void*)g,
        (__attribute__((address_space(3))) void*)lds, 16, 0, 0);
}

// ---------------------------------------------------------------------------
// 512-thread split-K(x2)-in-block MFMA GEMM (BNK-true): C = A @ B^T*scale+bias
// CVEC: additionally cvec[m] += cscale * sum_n C[m][n]*bk[n] (atomic).
// ---------------------------------------------------------------------------
template<bool CVEC>
__global__ __launch_bounds__(512)
void gemm_bt_512(const float* __restrict__ A, const float* __restrict__ Bm,
                 const float* __restrict__ bias, float* __restrict__ C,
                 float scale, const float* __restrict__ bk,
                 float* __restrict__ cvec, float cscale)
{
    const int m0 = blockIdx.x * 64;
    const int n0 = blockIdx.y * 64;
    const int t   = threadIdx.x;
    const int w   = t >> 6;
    const int wm  = w & 3;      // m-subtile
    const int kh  = w >> 2;     // k-half
    const int l   = t & 63;
    const int row = l & 15;
    const int kg  = l >> 4;

    const float* ap = A + (size_t)(m0 + wm * 16 + row) * H + kh * 512 + kg * 8;
    const float* bp = Bm + (size_t)(n0 + row) * H + kh * 512 + kg * 8;

    f32x4 acc[4] = {};
    for (int k0 = 0; k0 < 512; k0 += 32) {
        float a8[8];
        *reinterpret_cast<float4*>(&a8[0]) = *reinterpret_cast<const float4*>(ap + k0);
        *reinterpret_cast<float4*>(&a8[4]) = *reinterpret_cast<const float4*>(ap + k0 + 4);
        bf16x8 ahi, alo;
        split_bf16(a8, ahi, alo);
        #pragma unroll
        for (int j = 0; j < 4; ++j) {
            float b8[8];
            const float* bjp = bp + (size_t)j * 16 * H + k0;
            *reinterpret_cast<float4*>(&b8[0]) = *reinterpret_cast<const float4*>(bjp);
            *reinterpret_cast<float4*>(&b8[4]) = *reinterpret_cast<const float4*>(bjp + 4);
            bf16x8 bhi, blo;
            split_bf16(b8, bhi, blo);
            acc[j] = __builtin_amdgcn_mfma_f32_16x16x32_bf16(ahi, bhi, acc[j], 0, 0, 0);
            acc[j] = __builtin_amdgcn_mfma_f32_16x16x32_bf16(ahi, blo, acc[j], 0, 0, 0);
            acc[j] = __builtin_amdgcn_mfma_f32_16x16x32_bf16(alo, bhi, acc[j], 0, 0, 0);
        }
    }

    __shared__ f32x4 red[4][4][64];   // partials from kh==1 waves (16 KB)
    if (kh == 1) {
        #pragma unroll
        for (int j = 0; j < 4; ++j) red[wm][j][l] = acc[j];
    }
    __syncthreads();
    if (kh == 0) {
        float p[4] = {0.f, 0.f, 0.f, 0.f};
        #pragma unroll
        for (int j = 0; j < 4; ++j) {
            f32x4 s = acc[j] + red[wm][j][l];
            int n = n0 + j * 16 + row;
            float bb = bias ? bias[n] : 0.f;
            float bkv = CVEC ? bk[n] : 0.f;
            #pragma unroll
            for (int r = 0; r < 4; ++r) {
                int m = m0 + wm * 16 + kg * 4 + r;
                float o = s[r] * scale + bb;
                C[(size_t)m * H + n] = o;
                if (CVEC) p[r] += o * bkv;
            }
        }
        if (CVEC) {
            #pragma unroll
            for (int r = 0; r < 4; ++r) {
                #pragma unroll
                for (int off = 1; off < 16; off <<= 1)
                    p[r] += __shfl_xor(p[r], off);
            }
            if (row == 0) {
                #pragma unroll
                for (int r = 0; r < 4; ++r)
                    atomicAdd(&cvec[m0 + wm * 16 + kg * 4 + r], p[r] * cscale);
            }
        }
    }
}

// ---------------------------------------------------------------------------
// N-proj, B read strided directly from Wk[k][n]: N = (q @ Wk) * scale
// -> pre-split bf16 hi/lo [m][n]. 512-thr split-K(x2).
// ---------------------------------------------------------------------------
__global__ __launch_bounds__(512)
void ngemm_direct(const float* __restrict__ A, const float* __restrict__ Wk,
                  __bf16* __restrict__ Nhi, __bf16* __restrict__ Nlo, float scale)
{
    const int m0 = blockIdx.x * 64;
    const int n0 = blockIdx.y * 64;
    const int t   = threadIdx.x;
    const int w   = t >> 6;
    const int wm  = w & 3;
    const int kh  = w >> 2;
    const int l   = t & 63;
    const int row = l & 15;
    const int kg  = l >> 4;

    const float* ap = A + (size_t)(m0 + wm * 16 + row) * H + kh * 512 + kg * 8;
    const float* bp = Wk + (size_t)(kh * 512 + kg * 8) * H + n0 + row;

    f32x4 acc[4] = {};
    for (int k0 = 0; k0 < 512; k0 += 32) {
        float a8[8];
        *reinterpret_cast<float4*>(&a8[0]) = *reinterpret_cast<const float4*>(ap + k0);
        *reinterpret_cast<float4*>(&a8[4]) = *reinterpret_cast<const float4*>(ap + k0 + 4);
        bf16x8 ahi, alo;
        split_bf16(a8, ahi, alo);
        #pragma unroll
        for (int j = 0; j < 4; ++j) {
            float b8[8];
            #pragma unroll
            for (int e = 0; e < 8; ++e)
                b8[e] = bp[(size_t)(k0 + e) * H + j * 16];
            bf16x8 bhi, blo;
            split_bf16(b8, bhi, blo);
            acc[j] = __builtin_amdgcn_mfma_f32_16x16x32_bf16(ahi, bhi, acc[j], 0, 0, 0);
            acc[j] = __builtin_amdgcn_mfma_f32_16x16x32_bf16(ahi, blo, acc[j], 0, 0, 0);
            acc[j] = __builtin_amdgcn_mfma_f32_16x16x32_bf16(alo, bhi, acc[j], 0, 0, 0);
        }
    }

    __shared__ f32x4 red[4][4][64];
    if (kh == 1) {
        #pragma unroll
        for (int j = 0; j < 4; ++j) red[wm][j][l] = acc[j];
    }
    __syncthreads();
    if (kh == 0) {
        #pragma unroll
        for (int j = 0; j < 4; ++j) {
            f32x4 s = acc[j] + red[wm][j][l];
            int n = n0 + j * 16 + row;
            #pragma unroll
            for (int r = 0; r < 4; ++r) {
                int m = m0 + wm * 16 + kg * 4 + r;
                float v = s[r] * scale;
                __bf16 hi = (__bf16)v;
                Nhi[(size_t)m * H + n] = hi;
                Nlo[(size_t)m * H + n] = (__bf16)(v - (float)hi);
            }
        }
    }
}

// ---------------------------------------------------------------------------
// scores[b,s,qi] = sum_h keys[b,s,h]*N[b,qi,h] + c[b,qi]
// 64-k chunks; DOUBLE-buffered XOR-swizzled N LDS; ONE barrier per chunk;
// next chunk's keys+N register loads issued AFTER the barrier so they fly
// during the whole compute phase. 512 thr (8 waves x 16 s). Fused softmax
// partial stats. XCD swizzle.
// ---------------------------------------------------------------------------
__global__ __launch_bounds__(512, 4)
void scores_mfma(const float* __restrict__ keys,
                 const __bf16* __restrict__ Nhi, const __bf16* __restrict__ Nlo,
                 const float* __restrict__ cvec, float* __restrict__ scores,
                 float* __restrict__ pmax, float* __restrict__ psum)
{
    const int id = blockIdx.x;          // 512 blocks
    const int x  = id & 7;
    const int m  = id >> 3;             // 0..63
    const int b  = 2 * x + (m >> 5);    // 2 batches per XCD
    const int ch = m & 31;
    const int s0 = ch * 128;

    const int t   = threadIdx.x;
    const int w   = t >> 6;             // 0..7
    const int l   = t & 63;
    const int row = l & 15;
    const int kg  = l >> 4;

    __shared__ __bf16 nshH[2][64][8][8];  // [buf][qi][slot][e] (16 KB)
    __shared__ __bf16 nshL[2][64][8][8];  // 16 KB
    __shared__ float redm[8][64];         // 2 KB

    const float* ka = keys + ((size_t)b * SEQ + s0 + w * 16 + row) * H + kg * 8;
    const __bf16* nhb = Nhi + (size_t)b * BQ * H;
    const __bf16* nlb = Nlo + (size_t)b * BQ * H;

    // staging: thread t covers (qi = t>>3, kb = t&7) of the 64x64 chunk
    const int sqi = t >> 3;
    const int skb = t & 7;
    const int ssl = skb ^ (sqi & 7);

    // prologue: chunk 0 into reg set 0
    float4 kr[2][4];
    bf16x8 nh[2], nl[2];
    #pragma unroll
    for (int ii = 0; ii < 2; ++ii) {
        kr[0][2 * ii + 0] = *reinterpret_cast<const float4*>(ka + ii * 32);
        kr[0][2 * ii + 1] = *reinterpret_cast<const float4*>(ka + ii * 32 + 4);
    }
    {
        size_t go = (size_t)sqi * H + skb * 8;
        nh[0] = *reinterpret_cast<const bf16x8*>(nhb + go);
        nl[0] = *reinterpret_cast<const bf16x8*>(nlb + go);
    }

    f32x4 acc[4] = {};
    #pragma unroll
    for (int c = 0; c < 16; ++c) {
        const int buf = c & 1;
        // write N(c) regs -> LDS[buf] (waits vmcnt for those loads)
        *reinterpret_cast<bf16x8*>(&nshH[buf][sqi][ssl][0]) = nh[buf];
        *reinterpret_cast<bf16x8*>(&nshL[buf][sqi][ssl][0]) = nl[buf];
        __syncthreads();
        // issue chunk c+1 loads AFTER the barrier -> in flight during compute
        if (c < 15) {
            const int kc = (c + 1) * 64;
            #pragma unroll
            for (int ii = 0; ii < 2; ++ii) {
                kr[buf ^ 1][2 * ii + 0] = *reinterpret_cast<const float4*>(ka + kc + ii * 32);
                kr[buf ^ 1][2 * ii + 1] = *reinterpret_cast<const float4*>(ka + kc + ii * 32 + 4);
            }
            size_t go = (size_t)sqi * H + kc + skb * 8;
            nh[buf ^ 1] = *reinterpret_cast<const bf16x8*>(nhb + go);
            nl[buf ^ 1] = *reinterpret_cast<const bf16x8*>(nlb + go);
        }
        // compute chunk c from kr[buf] + LDS[buf]
        #pragma unroll
        for (int ii = 0; ii < 2; ++ii) {
            float a8[8];
            *reinterpret_cast<float4*>(&a8[0]) = kr[buf][2 * ii + 0];
            *reinterpret_cast<float4*>(&a8[4]) = kr[buf][2 * ii + 1];
            bf16x8 ahi, alo;
            split_bf16(a8, ahi, alo);
            const int kb = ii * 4 + kg;
            const int slot = kb ^ (row & 7);
            #pragma unroll
            for (int j = 0; j < 4; ++j) {
                const int qi = j * 16 + row;
                bf16x8 bhi = *reinterpret_cast<const bf16x8*>(&nshH[buf][qi][slot][0]);
                bf16x8 blo = *reinterpret_cast<const bf16x8*>(&nshL[buf][qi][slot][0]);
                acc[j] = __builtin_amdgcn_mfma_f32_16x16x32_bf16(ahi, bhi, acc[j], 0, 0, 0);
                acc[j] = __builtin_amdgcn_mfma_f32_16x16x32_bf16(ahi, blo, acc[j], 0, 0, 0);
                acc[j] = __builtin_amdgcn_mfma_f32_16x16x32_bf16(alo, bhi, acc[j], 0, 0, 0);
            }
        }
    }

    // epilogue: add cvec, write scores
    #pragma unroll
    for (int j = 0; j < 4; ++j) {
        int qi = j * 16 + row;
        float cv = cvec[b * BQ + qi];
        #pragma unroll
        for (int r = 0; r < 4; ++r) {
            acc[j][r] += cv;
            int s = s0 + w * 16 + kg * 4 + r;
            scores[((size_t)b * SEQ + s) * BQ + qi] = acc[j][r];
        }
    }
    // fused partial stats over this block's 128 s-rows
    float mj[4];
    #pragma unroll
    for (int j = 0; j < 4; ++j) {
        float mm = fmaxf(fmaxf(acc[j][0], acc[j][1]), fmaxf(acc[j][2], acc[j][3]));
        mm = fmaxf(mm, __shfl_xor(mm, 16));
        mm = fmaxf(mm, __shfl_xor(mm, 32));
        mj[j] = mm;
    }
    __syncthreads();
    if (kg == 0) {
        #pragma unroll
        for (int j = 0; j < 4; ++j) redm[w][j * 16 + row] = mj[j];
    }
    __syncthreads();
    float Mj[4];
    #pragma unroll
    for (int j = 0; j < 4; ++j) {
        const int qi = j * 16 + row;
        float M = redm[0][qi];
        #pragma unroll
        for (int ww = 1; ww < 8; ++ww) M = fmaxf(M, redm[ww][qi]);
        Mj[j] = M;
    }
    float sj[4];
    #pragma unroll
    for (int j = 0; j < 4; ++j) {
        float s = 0.f;
        #pragma unroll
        for (int r = 0; r < 4; ++r) s += __expf(acc[j][r] - Mj[j]);
        s += __shfl_xor(s, 16);
        s += __shfl_xor(s, 32);
        sj[j] = s;
    }
    __syncthreads();
    if (kg == 0) {
        #pragma unroll
        for (int j = 0; j < 4; ++j) redm[w][j * 16 + row] = sj[j];
    }
    __syncthreads();
    if (w == 0 && kg == 0) {
        #pragma unroll
        for (int j = 0; j < 4; ++j) {
            const int qi = j * 16 + row;
            float ss = 0.f;
            #pragma unroll
            for (int ww = 0; ww < 8; ++ww) ss += redm[ww][qi];
            pmax[((size_t)b * 32 + ch) * 64 + qi] = Mj[j];
            psum[((size_t)b * 32 + ch) * 64 + qi] = ss;
        }
    }
}

// ---------------------------------------------------------------------------
// normalize in place (inline global-stat combine) + bf16 transposed copy
// ---------------------------------------------------------------------------
__global__ __launch_bounds__(256)
void sm_norm(float* __restrict__ attn, const float* __restrict__ pmax,
             const float* __restrict__ psum, __hip_bfloat16* __restrict__ abfT)
{
    __shared__ float tile[64][133];
    const int b  = blockIdx.y;
    const int ch = blockIdx.x;
    const int t  = threadIdx.x;
    const int qi = t & 63;
    const int g  = t >> 6;

    // inline combine of 32 chunk-stats for this (b,qi)
    float M = -1e30f;
    #pragma unroll 4
    for (int c = 0; c < 32; ++c)
        M = fmaxf(M, pmax[((size_t)b * 32 + c) * 64 + qi]);
    float ssum = 0.f;
    #pragma unroll 4
    for (int c = 0; c < 32; ++c)
        ssum += psum[((size_t)b * 32 + c) * 64 + qi] *
                __expf(pmax[((size_t)b * 32 + c) * 64 + qi] - M);
    const float inv = 1.f / ssum;

    float* sb = attn + ((size_t)b * SEQ + ch * 128) * BQ;
    #pragma unroll 8
    for (int i = 0; i < 32; ++i) {
        int sl = g + i * 4;
        size_t idx = (size_t)sl * BQ + qi;
        float w = __expf(sb[idx] - M) * inv;
        sb[idx] = w;
        tile[qi][sl] = w;
    }
    __syncthreads();
    const int qo = t >> 2;
    const int c  = (t & 3) * 32;
    __hip_bfloat16* dst = abfT + ((size_t)(b * BQ + qo)) * SEQ + ch * 128 + c;
    #pragma unroll
    for (int v = 0; v < 4; ++v) {
        bf16x8 w8;
        #pragma unroll
        for (int e = 0; e < 8; ++e)
            w8[e] = (__bf16)tile[qo][c + v * 8 + e];
        *reinterpret_cast<bf16x8*>(dst + v * 8) = w8;
    }
}

// ---------------------------------------------------------------------------
// Tpart[sc][b][qi][h] = sum_{s in chunk} abfT[b,qi,s] * values[b,s,h]
// values staged via global_load_lds (dbuf, pre-swizzled source col).
// ---------------------------------------------------------------------------
template<int SC>
__global__ __launch_bounds__(256)
void tmat_mfma(const __hip_bfloat16* __restrict__ abfT,
               const float* __restrict__ values,
               float* __restrict__ Tpart)
{
    const int i  = blockIdx.x;
    const int h0 = ((i >> 3) & 7) * 128;
    const int g  = (i & 7) + 8 * (i >> 6);
    const int b  = g / SC;
    const int sc = g % SC;
    const int schunk = SEQ / SC;

    const int w   = threadIdx.x >> 6;
    const int l   = threadIdx.x & 63;
    const int row = l & 15;
    const int kg  = l >> 4;
    const int sbase = sc * schunk;

    __shared__ float vlds[2][32][128];   // 32 KB

    const __hip_bfloat16* ap = abfT + ((size_t)b * BQ + row) * SEQ + sbase + kg * 8;
    const float* vb = values + ((size_t)b * SEQ + sbase) * H + h0;

    const int nk = schunk / 32;

    #define STAGE(buf, k0)                                                     \
        {                                                                      \
            _Pragma("unroll")                                                  \
            for (int ii = 0; ii < 4; ++ii) {                                   \
                int elem = w * 1024 + ii * 256 + l * 4;                        \
                int k    = elem >> 7;                                          \
                int cc   = elem & 127;                                         \
                int csw  = cc ^ ((k >> 3) << 4);                               \
                const float* src = vb + (size_t)((k0) + k) * H + csw;          \
                gload_lds16(src, (void*)(&vlds[buf][0][0] + w * 1024 + ii * 256)); \
            }                                                                  \
        }

    f32x4 acc[4][2] = {};
    STAGE(0, 0);
    __syncthreads();

    for (int ks = 0; ks < nk; ++ks) {
        const int buf = ks & 1;
        if (ks + 1 < nk) STAGE(buf ^ 1, (ks + 1) * 32);
        const int k0 = ks * 32;
        bf16x8 a[4];
        #pragma unroll
        for (int q = 0; q < 4; ++q)
            a[q] = *reinterpret_cast<const bf16x8*>(ap + (size_t)q * 16 * SEQ + k0);
        #pragma unroll
        for (int j = 0; j < 2; ++j) {
            const int col = (w * 32 + j * 16 + row) ^ (kg << 4);
            float b8[8];
            #pragma unroll
            for (int e = 0; e < 8; ++e)
                b8[e] = vlds[buf][kg * 8 + e][col];
            bf16x8 bhi, blo;
            split_bf16(b8, bhi, blo);
            #pragma unroll
            for (int q = 0; q < 4; ++q) {
                acc[q][j] = __builtin_amdgcn_mfma_f32_16x16x32_bf16(a[q], bhi, acc[q][j], 0, 0, 0);
                acc[q][j] = __builtin_amdgcn_mfma_f32_16x16x32_bf16(a[q], blo, acc[q][j], 0, 0, 0);
            }
        }
        __syncthreads();
    }
    #undef STAGE

    float* tp = Tpart + ((size_t)sc * NB + b) * BQ * H;
    #pragma unroll
    for (int q = 0; q < 4; ++q) {
        #pragma unroll
        for (int j = 0; j < 2; ++j) {
            int h = h0 + w * 32 + j * 16 + row;
            #pragma unroll
            for (int r = 0; r < 4; ++r) {
                int qi = q * 16 + kg * 4 + r;
                tp[(size_t)qi * H + h] = acc[q][j][r];
            }
        }
    }
}

// ---------------------------------------------------------------------------
// In-place partial reduction: Tpart[0][i] = sum_p Tpart[p][i]
// ---------------------------------------------------------------------------
template<int SC>
__global__ __launch_bounds__(256)
void tsum_kernel(float* __restrict__ Tpart)
{
    const size_t stride = (size_t)NB * BQ * H;
    size_t i = ((size_t)blockIdx.x * 256 + threadIdx.x) * 4;
    f32x4 s = *reinterpret_cast<const f32x4*>(Tpart + i);
    #pragma unroll
    for (int p = 1; p < SC; ++p)
        s += *reinterpret_cast<const f32x4*>(Tpart + p * stride + i);
    *reinterpret_cast<f32x4*>(Tpart + i) = s;
}

// ---------------------------------------------------------------------------
extern "C" void kernel_launch(void* const* d_in, const int* in_sizes, int n_in,
                              void* d_out, int out_size, void* d_ws, size_t ws_size,
                              hipStream_t stream)
{
    const float* queries = (const float*)d_in[0];
    const float* keys    = (const float*)d_in[1];
    const float* values  = (const float*)d_in[2];
    const float* Wq = (const float*)d_in[3];
    const float* bq = (const float*)d_in[4];
    const float* Wk = (const float*)d_in[5];
    const float* bk = (const float*)d_in[6];
    const float* Wv = (const float*)d_in[7];
    const float* bv = (const float*)d_in[8];

    float* out     = (float*)d_out;
    float* context = out;                          // 16*64*1024 f32
    float* attn    = out + (size_t)NB * BQ * H;    // 16*4096*64 f32

    const int SC = (ws_size >= (41ull << 20)) ? 8 : 2;

    char* ws = (char*)d_ws;
    float* q     = (float*)ws;                              // 4 MB  [0,4)
    __bf16* Nhi  = (__bf16*)(ws + (8ull << 20));            // 2 MB  [8,10)
    __bf16* Nlo  = (__bf16*)(ws + (10ull << 20));           // 2 MB  [10,12)
    float* Tpart = (float*)ws;                              // SC*4 MB (overlaps q/N, dead by tmat)
    __hip_bfloat16* abfT = (__hip_bfloat16*)(ws + (size_t)SC * (4ull << 20)); // 8 MB
    char* smalls = ws + (size_t)SC * (4ull << 20) + (8ull << 20);
    float* cvec  = (float*)smalls;                          // 4 KB
    float* pmax  = (float*)(smalls + (128u << 10));         // 128 KB
    float* psum  = (float*)(smalls + (512u << 10));         // 128 KB

    const float scale = 0.03125f; // 1/sqrt(1024)

    // cvec accumulated atomically in q-GEMM epilogue
    hipMemsetAsync(cvec, 0, (size_t)NB * BQ * sizeof(float), stream);
    // q = queries @ Wq^T + bq  (+ cvec = scale*(q . bk))
    gemm_bt_512<true><<<dim3(16, 16), 512, 0, stream>>>(
        queries, Wq, bq, q, 1.0f, bk, cvec, scale);
    // N = (q @ Wk) * scale -> pre-split bf16 hi/lo (Wk read strided, no transpose)
    ngemm_direct<<<dim3(16, 16), 512, 0, stream>>>(q, Wk, Nhi, Nlo, scale);
    // scores + fused per-chunk softmax stats
    scores_mfma<<<512, 512, 0, stream>>>(keys, Nhi, Nlo, cvec, attn, pmax, psum);
    // normalize (inline stat combine) + bf16 transposed copy
    sm_norm<<<dim3(32, NB), 256, 0, stream>>>(attn, pmax, psum, abfT);
    // T partials = attn^T @ values
    if (SC == 8) tmat_mfma<8><<<8 * NB * 8, 256, 0, stream>>>(abfT, values, Tpart);
    else         tmat_mfma<2><<<8 * NB * 2, 256, 0, stream>>>(abfT, values, Tpart);
    // Tsum (in place into partial 0)
    if (SC == 8) tsum_kernel<8><<<1024, 256, 0, stream>>>(Tpart);
    else         tsum_kernel<2><<<1024, 256, 0, stream>>>(Tpart);
    // context = Tsum @ Wv^T + bv
    gemm_bt_512<false><<<dim3(16, 16), 512, 0, stream>>>(
        Tpart, Wv, bv, context, 1.0f, nullptr, nullptr, 0.f);
}

// Round 17
// 277.683 us; speedup vs baseline: 1.2954x; 1.0163x over previous
//
#include <hip/hip_runtime.h>
#include <hip/hip_bf16.h>

#define H 1024
#define SEQ 4096
#define BQ 64   // Kq
#define NB 16   // batch

typedef float f32x4 __attribute__((ext_vector_type(4)));
typedef __bf16 bf16x8 __attribute__((ext_vector_type(8)));

__device__ __forceinline__ void split_bf16(const float* x, bf16x8& hi, bf16x8& lo)
{
    #pragma unroll
    for (int i = 0; i < 8; ++i) {
        float v = x[i];
        __bf16 h = (__bf16)v;
        hi[i] = h;
        lo[i] = (__bf16)(v - (float)h);
    }
}

__device__ __forceinline__ void gload_lds16(const void* g, void* lds)
{
    __builtin_amdgcn_global_load_lds(
        (const __attribute__((address_space(1))) void*)g,
        (__attribute__((address_space(3))) void*)lds, 16, 0, 0);
}

// ---------------------------------------------------------------------------
// 512-thread split-K(x2)-in-block MFMA GEMM (BNK-true): C = A @ B^T*scale+bias
// CVEC: additionally cvec[m] += cscale * sum_n C[m][n]*bk[n] (atomic).
// ---------------------------------------------------------------------------
template<bool CVEC>
__global__ __launch_bounds__(512)
void gemm_bt_512(const float* __restrict__ A, const float* __restrict__ Bm,
                 const float* __restrict__ bias, float* __restrict__ C,
                 float scale, const float* __restrict__ bk,
                 float* __restrict__ cvec, float cscale)
{
    const int m0 = blockIdx.x * 64;
    const int n0 = blockIdx.y * 64;
    const int t   = threadIdx.x;
    const int w   = t >> 6;
    const int wm  = w & 3;      // m-subtile
    const int kh  = w >> 2;     // k-half
    const int l   = t & 63;
    const int row = l & 15;
    const int kg  = l >> 4;

    const float* ap = A + (size_t)(m0 + wm * 16 + row) * H + kh * 512 + kg * 8;
    const float* bp = Bm + (size_t)(n0 + row) * H + kh * 512 + kg * 8;

    f32x4 acc[4] = {};
    for (int k0 = 0; k0 < 512; k0 += 32) {
        float a8[8];
        *reinterpret_cast<float4*>(&a8[0]) = *reinterpret_cast<const float4*>(ap + k0);
        *reinterpret_cast<float4*>(&a8[4]) = *reinterpret_cast<const float4*>(ap + k0 + 4);
        bf16x8 ahi, alo;
        split_bf16(a8, ahi, alo);
        #pragma unroll
        for (int j = 0; j < 4; ++j) {
            float b8[8];
            const float* bjp = bp + (size_t)j * 16 * H + k0;
            *reinterpret_cast<float4*>(&b8[0]) = *reinterpret_cast<const float4*>(bjp);
            *reinterpret_cast<float4*>(&b8[4]) = *reinterpret_cast<const float4*>(bjp + 4);
            bf16x8 bhi, blo;
            split_bf16(b8, bhi, blo);
            acc[j] = __builtin_amdgcn_mfma_f32_16x16x32_bf16(ahi, bhi, acc[j], 0, 0, 0);
            acc[j] = __builtin_amdgcn_mfma_f32_16x16x32_bf16(ahi, blo, acc[j], 0, 0, 0);
            acc[j] = __builtin_amdgcn_mfma_f32_16x16x32_bf16(alo, bhi, acc[j], 0, 0, 0);
        }
    }

    __shared__ f32x4 red[4][4][64];   // partials from kh==1 waves (16 KB)
    if (kh == 1) {
        #pragma unroll
        for (int j = 0; j < 4; ++j) red[wm][j][l] = acc[j];
    }
    __syncthreads();
    if (kh == 0) {
        float p[4] = {0.f, 0.f, 0.f, 0.f};
        #pragma unroll
        for (int j = 0; j < 4; ++j) {
            f32x4 s = acc[j] + red[wm][j][l];
            int n = n0 + j * 16 + row;
            float bb = bias ? bias[n] : 0.f;
            float bkv = CVEC ? bk[n] : 0.f;
            #pragma unroll
            for (int r = 0; r < 4; ++r) {
                int m = m0 + wm * 16 + kg * 4 + r;
                float o = s[r] * scale + bb;
                C[(size_t)m * H + n] = o;
                if (CVEC) p[r] += o * bkv;
            }
        }
        if (CVEC) {
            #pragma unroll
            for (int r = 0; r < 4; ++r) {
                #pragma unroll
                for (int off = 1; off < 16; off <<= 1)
                    p[r] += __shfl_xor(p[r], off);
            }
            if (row == 0) {
                #pragma unroll
                for (int r = 0; r < 4; ++r)
                    atomicAdd(&cvec[m0 + wm * 16 + kg * 4 + r], p[r] * cscale);
            }
        }
    }
}

// ---------------------------------------------------------------------------
// N-proj, B read strided directly from Wk[k][n]: N = (q @ Wk) * scale
// -> pre-split bf16 hi/lo [m][n]. 512-thr split-K(x2).
// ---------------------------------------------------------------------------
__global__ __launch_bounds__(512)
void ngemm_direct(const float* __restrict__ A, const float* __restrict__ Wk,
                  __bf16* __restrict__ Nhi, __bf16* __restrict__ Nlo, float scale)
{
    const int m0 = blockIdx.x * 64;
    const int n0 = blockIdx.y * 64;
    const int t   = threadIdx.x;
    const int w   = t >> 6;
    const int wm  = w & 3;
    const int kh  = w >> 2;
    const int l   = t & 63;
    const int row = l & 15;
    const int kg  = l >> 4;

    const float* ap = A + (size_t)(m0 + wm * 16 + row) * H + kh * 512 + kg * 8;
    const float* bp = Wk + (size_t)(kh * 512 + kg * 8) * H + n0 + row;

    f32x4 acc[4] = {};
    for (int k0 = 0; k0 < 512; k0 += 32) {
        float a8[8];
        *reinterpret_cast<float4*>(&a8[0]) = *reinterpret_cast<const float4*>(ap + k0);
        *reinterpret_cast<float4*>(&a8[4]) = *reinterpret_cast<const float4*>(ap + k0 + 4);
        bf16x8 ahi, alo;
        split_bf16(a8, ahi, alo);
        #pragma unroll
        for (int j = 0; j < 4; ++j) {
            float b8[8];
            #pragma unroll
            for (int e = 0; e < 8; ++e)
                b8[e] = bp[(size_t)(k0 + e) * H + j * 16];
            bf16x8 bhi, blo;
            split_bf16(b8, bhi, blo);
            acc[j] = __builtin_amdgcn_mfma_f32_16x16x32_bf16(ahi, bhi, acc[j], 0, 0, 0);
            acc[j] = __builtin_amdgcn_mfma_f32_16x16x32_bf16(ahi, blo, acc[j], 0, 0, 0);
            acc[j] = __builtin_amdgcn_mfma_f32_16x16x32_bf16(alo, bhi, acc[j], 0, 0, 0);
        }
    }

    __shared__ f32x4 red[4][4][64];
    if (kh == 1) {
        #pragma unroll
        for (int j = 0; j < 4; ++j) red[wm][j][l] = acc[j];
    }
    __syncthreads();
    if (kh == 0) {
        #pragma unroll
        for (int j = 0; j < 4; ++j) {
            f32x4 s = acc[j] + red[wm][j][l];
            int n = n0 + j * 16 + row;
            #pragma unroll
            for (int r = 0; r < 4; ++r) {
                int m = m0 + wm * 16 + kg * 4 + r;
                float v = s[r] * scale;
                __bf16 hi = (__bf16)v;
                Nhi[(size_t)m * H + n] = hi;
                Nlo[(size_t)m * H + n] = (__bf16)(v - (float)hi);
            }
        }
    }
}

// ---------------------------------------------------------------------------
// scores[b,s,qi] = sum_h keys[b,s,h]*N[b,qi,h] + c[b,qi]   (R13 structure)
// ---------------------------------------------------------------------------
__global__ __launch_bounds__(512, 4)
void scores_mfma(const float* __restrict__ keys,
                 const __bf16* __restrict__ Nhi, const __bf16* __restrict__ Nlo,
                 const float* __restrict__ cvec, float* __restrict__ scores,
                 float* __restrict__ pmax, float* __restrict__ psum)
{
    const int id = blockIdx.x;          // 512 blocks
    const int x  = id & 7;
    const int m  = id >> 3;             // 0..63
    const int b  = 2 * x + (m >> 5);    // 2 batches per XCD
    const int ch = m & 31;
    const int s0 = ch * 128;

    const int t   = threadIdx.x;
    const int w   = t >> 6;             // 0..7
    const int l   = t & 63;
    const int row = l & 15;
    const int kg  = l >> 4;

    __shared__ __bf16 nshH[2][64][8][8];  // [buf][qi][slot][e] (16 KB)
    __shared__ __bf16 nshL[2][64][8][8];  // 16 KB
    __shared__ float redm[8][64];         // 2 KB

    const float* ka = keys + ((size_t)b * SEQ + s0 + w * 16 + row) * H + kg * 8;
    const __bf16* nhb = Nhi + (size_t)b * BQ * H;
    const __bf16* nlb = Nlo + (size_t)b * BQ * H;

    const int sqi = t >> 3;
    const int skb = t & 7;
    const int ssl = skb ^ (sqi & 7);

    float4 kr[2][4];
    bf16x8 nh[2], nl[2];
    #pragma unroll
    for (int ii = 0; ii < 2; ++ii) {
        kr[0][2 * ii + 0] = *reinterpret_cast<const float4*>(ka + ii * 32);
        kr[0][2 * ii + 1] = *reinterpret_cast<const float4*>(ka + ii * 32 + 4);
    }
    {
        size_t go = (size_t)sqi * H + skb * 8;
        nh[0] = *reinterpret_cast<const bf16x8*>(nhb + go);
        nl[0] = *reinterpret_cast<const bf16x8*>(nlb + go);
    }

    f32x4 acc[4] = {};
    #pragma unroll
    for (int c = 0; c < 16; ++c) {
        const int buf = c & 1;
        *reinterpret_cast<bf16x8*>(&nshH[buf][sqi][ssl][0]) = nh[buf];
        *reinterpret_cast<bf16x8*>(&nshL[buf][sqi][ssl][0]) = nl[buf];
        __syncthreads();
        if (c < 15) {
            const int kc = (c + 1) * 64;
            #pragma unroll
            for (int ii = 0; ii < 2; ++ii) {
                kr[buf ^ 1][2 * ii + 0] = *reinterpret_cast<const float4*>(ka + kc + ii * 32);
                kr[buf ^ 1][2 * ii + 1] = *reinterpret_cast<const float4*>(ka + kc + ii * 32 + 4);
            }
            size_t go = (size_t)sqi * H + kc + skb * 8;
            nh[buf ^ 1] = *reinterpret_cast<const bf16x8*>(nhb + go);
            nl[buf ^ 1] = *reinterpret_cast<const bf16x8*>(nlb + go);
        }
        #pragma unroll
        for (int ii = 0; ii < 2; ++ii) {
            float a8[8];
            *reinterpret_cast<float4*>(&a8[0]) = kr[buf][2 * ii + 0];
            *reinterpret_cast<float4*>(&a8[4]) = kr[buf][2 * ii + 1];
            bf16x8 ahi, alo;
            split_bf16(a8, ahi, alo);
            const int kb = ii * 4 + kg;
            const int slot = kb ^ (row & 7);
            #pragma unroll
            for (int j = 0; j < 4; ++j) {
                const int qi = j * 16 + row;
                bf16x8 bhi = *reinterpret_cast<const bf16x8*>(&nshH[buf][qi][slot][0]);
                bf16x8 blo = *reinterpret_cast<const bf16x8*>(&nshL[buf][qi][slot][0]);
                acc[j] = __builtin_amdgcn_mfma_f32_16x16x32_bf16(ahi, bhi, acc[j], 0, 0, 0);
                acc[j] = __builtin_amdgcn_mfma_f32_16x16x32_bf16(ahi, blo, acc[j], 0, 0, 0);
                acc[j] = __builtin_amdgcn_mfma_f32_16x16x32_bf16(alo, bhi, acc[j], 0, 0, 0);
            }
        }
    }

    #pragma unroll
    for (int j = 0; j < 4; ++j) {
        int qi = j * 16 + row;
        float cv = cvec[b * BQ + qi];
        #pragma unroll
        for (int r = 0; r < 4; ++r) {
            acc[j][r] += cv;
            int s = s0 + w * 16 + kg * 4 + r;
            scores[((size_t)b * SEQ + s) * BQ + qi] = acc[j][r];
        }
    }
    float mj[4];
    #pragma unroll
    for (int j = 0; j < 4; ++j) {
        float mm = fmaxf(fmaxf(acc[j][0], acc[j][1]), fmaxf(acc[j][2], acc[j][3]));
        mm = fmaxf(mm, __shfl_xor(mm, 16));
        mm = fmaxf(mm, __shfl_xor(mm, 32));
        mj[j] = mm;
    }
    __syncthreads();
    if (kg == 0) {
        #pragma unroll
        for (int j = 0; j < 4; ++j) redm[w][j * 16 + row] = mj[j];
    }
    __syncthreads();
    float Mj[4];
    #pragma unroll
    for (int j = 0; j < 4; ++j) {
        const int qi = j * 16 + row;
        float M = redm[0][qi];
        #pragma unroll
        for (int ww = 1; ww < 8; ++ww) M = fmaxf(M, redm[ww][qi]);
        Mj[j] = M;
    }
    float sj[4];
    #pragma unroll
    for (int j = 0; j < 4; ++j) {
        float s = 0.f;
        #pragma unroll
        for (int r = 0; r < 4; ++r) s += __expf(acc[j][r] - Mj[j]);
        s += __shfl_xor(s, 16);
        s += __shfl_xor(s, 32);
        sj[j] = s;
    }
    __syncthreads();
    if (kg == 0) {
        #pragma unroll
        for (int j = 0; j < 4; ++j) redm[w][j * 16 + row] = sj[j];
    }
    __syncthreads();
    if (w == 0 && kg == 0) {
        #pragma unroll
        for (int j = 0; j < 4; ++j) {
            const int qi = j * 16 + row;
            float ss = 0.f;
            #pragma unroll
            for (int ww = 0; ww < 8; ++ww) ss += redm[ww][qi];
            pmax[((size_t)b * 32 + ch) * 64 + qi] = Mj[j];
            psum[((size_t)b * 32 + ch) * 64 + qi] = ss;
        }
    }
}

// ---------------------------------------------------------------------------
// normalize in place (inline global-stat combine) + bf16 transposed copy
// ---------------------------------------------------------------------------
__global__ __launch_bounds__(256)
void sm_norm(float* __restrict__ attn, const float* __restrict__ pmax,
             const float* __restrict__ psum, __hip_bfloat16* __restrict__ abfT)
{
    __shared__ float tile[64][133];
    const int b  = blockIdx.y;
    const int ch = blockIdx.x;
    const int t  = threadIdx.x;
    const int qi = t & 63;
    const int g  = t >> 6;

    float M = -1e30f;
    #pragma unroll 4
    for (int c = 0; c < 32; ++c)
        M = fmaxf(M, pmax[((size_t)b * 32 + c) * 64 + qi]);
    float ssum = 0.f;
    #pragma unroll 4
    for (int c = 0; c < 32; ++c)
        ssum += psum[((size_t)b * 32 + c) * 64 + qi] *
                __expf(pmax[((size_t)b * 32 + c) * 64 + qi] - M);
    const float inv = 1.f / ssum;

    float* sb = attn + ((size_t)b * SEQ + ch * 128) * BQ;
    #pragma unroll 8
    for (int i = 0; i < 32; ++i) {
        int sl = g + i * 4;
        size_t idx = (size_t)sl * BQ + qi;
        float w = __expf(sb[idx] - M) * inv;
        sb[idx] = w;
        tile[qi][sl] = w;
    }
    __syncthreads();
    const int qo = t >> 2;
    const int c  = (t & 3) * 32;
    __hip_bfloat16* dst = abfT + ((size_t)(b * BQ + qo)) * SEQ + ch * 128 + c;
    #pragma unroll
    for (int v = 0; v < 4; ++v) {
        bf16x8 w8;
        #pragma unroll
        for (int e = 0; e < 8; ++e)
            w8[e] = (__bf16)tile[qo][c + v * 8 + e];
        *reinterpret_cast<bf16x8*>(dst + v * 8) = w8;
    }
}

// ---------------------------------------------------------------------------
// Tpart[sc][b][qi][h] = sum_{s in chunk} abfT[b,qi,s] * values[b,s,h]
// ALL operands staged via global_load_lds; 3-buffer pipeline staged 2 tiles
// ahead; counted s_waitcnt vmcnt(N) + raw s_barrier (no vmem drain) — T3/T4.
// ---------------------------------------------------------------------------
template<int SC>
__global__ __launch_bounds__(256)
void tmat_mfma(const __hip_bfloat16* __restrict__ abfT,
               const float* __restrict__ values,
               float* __restrict__ Tpart)
{
    constexpr int schunk = SEQ / SC;
    constexpr int nk = schunk / 32;

    const int i  = blockIdx.x;
    const int h0 = ((i >> 3) & 7) * 128;
    const int g  = (i & 7) + 8 * (i >> 6);
    const int b  = g / SC;
    const int sc = g % SC;

    const int w   = threadIdx.x >> 6;
    const int l   = threadIdx.x & 63;
    const int row = l & 15;
    const int kg  = l >> 4;
    const int sbase = sc * schunk;

    __shared__ float vlds[3][32][128];            // 48 KB
    __shared__ __hip_bfloat16 alds[3][64][32];    // 12 KB

    const __hip_bfloat16* ab = abfT + (size_t)b * BQ * SEQ + sbase;
    const float* vb = values + ((size_t)b * SEQ + sbase) * H + h0;

    // V tile [32 k][128 h]: 4 gloads/thread, linear dest, source col-swizzled
    #define VSTAGE(buf, c)                                                     \
        {                                                                      \
            _Pragma("unroll")                                                  \
            for (int ii = 0; ii < 4; ++ii) {                                   \
                int elem = w * 1024 + ii * 256 + l * 4;                        \
                int k    = elem >> 7;                                          \
                int cc   = elem & 127;                                         \
                int csw  = cc ^ ((k >> 3) << 4);                               \
                const float* src = vb + (size_t)((c) * 32 + k) * H + csw;      \
                gload_lds16(src, (void*)(&vlds[buf][0][0] + w * 1024 + ii * 256)); \
            }                                                                  \
        }
    // A tile [64 qi][32 k] bf16: 1 gload/thread; dest linear == [qi][col]
    #define ASTAGE(buf, c)                                                     \
        {                                                                      \
            int aqi = w * 16 + (l >> 2);                                       \
            const __hip_bfloat16* srcA =                                       \
                ab + (size_t)aqi * SEQ + (c) * 32 + (l & 3) * 8;               \
            gload_lds16(srcA, (void*)(&alds[buf][0][0] + w * 512));            \
        }

    f32x4 acc[4][2] = {};
    ASTAGE(0, 0); VSTAGE(0, 0);
    ASTAGE(1, 1); VSTAGE(1, 1);

    for (int ks = 0; ks < nk; ++ks) {
        const int buf = ks % 3;
        // issue stage ks+2, then wait so that stage ks is fully landed
        if (ks + 2 < nk) {
            const int nb2 = (ks + 2) % 3;
            ASTAGE(nb2, ks + 2); VSTAGE(nb2, ks + 2);
            asm volatile("s_waitcnt vmcnt(10)" ::: "memory");
        } else if (ks + 1 < nk) {
            asm volatile("s_waitcnt vmcnt(5)" ::: "memory");
        } else {
            asm volatile("s_waitcnt vmcnt(0)" ::: "memory");
        }
        __builtin_amdgcn_sched_barrier(0);
        __builtin_amdgcn_s_barrier();      // tile ks visible to all waves
        __builtin_amdgcn_sched_barrier(0);

        // compute tile ks from LDS
        bf16x8 a[4];
        #pragma unroll
        for (int q = 0; q < 4; ++q)
            a[q] = *reinterpret_cast<const bf16x8*>(&alds[buf][q * 16 + row][kg * 8]);
        #pragma unroll
        for (int j = 0; j < 2; ++j) {
            const int col = (w * 32 + j * 16 + row) ^ (kg << 4);
            float b8[8];
            #pragma unroll
            for (int e = 0; e < 8; ++e)
                b8[e] = vlds[buf][kg * 8 + e][col];
            bf16x8 bhi, blo;
            split_bf16(b8, bhi, blo);
            #pragma unroll
            for (int q = 0; q < 4; ++q) {
                acc[q][j] = __builtin_amdgcn_mfma_f32_16x16x32_bf16(a[q], bhi, acc[q][j], 0, 0, 0);
                acc[q][j] = __builtin_amdgcn_mfma_f32_16x16x32_bf16(a[q], blo, acc[q][j], 0, 0, 0);
            }
        }
        __builtin_amdgcn_sched_barrier(0);
        __builtin_amdgcn_s_barrier();      // compute(ks) done everywhere ->
        __builtin_amdgcn_sched_barrier(0); // buf may be overwritten next iter
    }
    #undef VSTAGE
    #undef ASTAGE

    float* tp = Tpart + ((size_t)sc * NB + b) * BQ * H;
    #pragma unroll
    for (int q = 0; q < 4; ++q) {
        #pragma unroll
        for (int j = 0; j < 2; ++j) {
            int h = h0 + w * 32 + j * 16 + row;
            #pragma unroll
            for (int r = 0; r < 4; ++r) {
                int qi = q * 16 + kg * 4 + r;
                tp[(size_t)qi * H + h] = acc[q][j][r];
            }
        }
    }
}

// ---------------------------------------------------------------------------
// In-place partial reduction: Tpart[0][i] = sum_p Tpart[p][i]
// ---------------------------------------------------------------------------
template<int SC>
__global__ __launch_bounds__(256)
void tsum_kernel(float* __restrict__ Tpart)
{
    const size_t stride = (size_t)NB * BQ * H;
    size_t i = ((size_t)blockIdx.x * 256 + threadIdx.x) * 4;
    f32x4 s = *reinterpret_cast<const f32x4*>(Tpart + i);
    #pragma unroll
    for (int p = 1; p < SC; ++p)
        s += *reinterpret_cast<const f32x4*>(Tpart + p * stride + i);
    *reinterpret_cast<f32x4*>(Tpart + i) = s;
}

// ---------------------------------------------------------------------------
extern "C" void kernel_launch(void* const* d_in, const int* in_sizes, int n_in,
                              void* d_out, int out_size, void* d_ws, size_t ws_size,
                              hipStream_t stream)
{
    const float* queries = (const float*)d_in[0];
    const float* keys    = (const float*)d_in[1];
    const float* values  = (const float*)d_in[2];
    const float* Wq = (const float*)d_in[3];
    const float* bq = (const float*)d_in[4];
    const float* Wk = (const float*)d_in[5];
    const float* bk = (const float*)d_in[6];
    const float* Wv = (const float*)d_in[7];
    const float* bv = (const float*)d_in[8];

    float* out     = (float*)d_out;
    float* context = out;                          // 16*64*1024 f32
    float* attn    = out + (size_t)NB * BQ * H;    // 16*4096*64 f32

    const int SC = (ws_size >= (41ull << 20)) ? 8 : 2;

    char* ws = (char*)d_ws;
    float* q     = (float*)ws;                              // 4 MB  [0,4)
    __bf16* Nhi  = (__bf16*)(ws + (8ull << 20));            // 2 MB  [8,10)
    __bf16* Nlo  = (__bf16*)(ws + (10ull << 20));           // 2 MB  [10,12)
    float* Tpart = (float*)ws;                              // SC*4 MB (overlaps q/N, dead by tmat)
    __hip_bfloat16* abfT = (__hip_bfloat16*)(ws + (size_t)SC * (4ull << 20)); // 8 MB
    char* smalls = ws + (size_t)SC * (4ull << 20) + (8ull << 20);
    float* cvec  = (float*)smalls;                          // 4 KB
    float* pmax  = (float*)(smalls + (128u << 10));         // 128 KB
    float* psum  = (float*)(smalls + (512u << 10));         // 128 KB

    const float scale = 0.03125f; // 1/sqrt(1024)

    // cvec accumulated atomically in q-GEMM epilogue
    hipMemsetAsync(cvec, 0, (size_t)NB * BQ * sizeof(float), stream);
    // q = queries @ Wq^T + bq  (+ cvec = scale*(q . bk))
    gemm_bt_512<true><<<dim3(16, 16), 512, 0, stream>>>(
        queries, Wq, bq, q, 1.0f, bk, cvec, scale);
    // N = (q @ Wk) * scale -> pre-split bf16 hi/lo (Wk read strided, no transpose)
    ngemm_direct<<<dim3(16, 16), 512, 0, stream>>>(q, Wk, Nhi, Nlo, scale);
    // scores + fused per-chunk softmax stats
    scores_mfma<<<512, 512, 0, stream>>>(keys, Nhi, Nlo, cvec, attn, pmax, psum);
    // normalize (inline stat combine) + bf16 transposed copy
    sm_norm<<<dim3(32, NB), 256, 0, stream>>>(attn, pmax, psum, abfT);
    // T partials = attn^T @ values (counted-vmcnt 3-buffer pipeline)
    if (SC == 8) tmat_mfma<8><<<8 * NB * 8, 256, 0, stream>>>(abfT, values, Tpart);
    else         tmat_mfma<2><<<8 * NB * 2, 256, 0, stream>>>(abfT, values, Tpart);
    // Tsum (in place into partial 0)
    if (SC == 8) tsum_kernel<8><<<1024, 256, 0, stream>>>(Tpart);
    else         tsum_kernel<2><<<1024, 256, 0, stream>>>(Tpart);
    // context = Tsum @ Wv^T + bv
    gemm_bt_512<false><<<dim3(16, 16), 512, 0, stream>>>(
        Tpart, Wv, bv, context, 1.0f, nullptr, nullptr, 0.f);
}

// Round 18
// 277.096 us; speedup vs baseline: 1.2981x; 1.0021x over previous
//
#include <hip/hip_runtime.h>
#include <hip/hip_bf16.h>

#define H 1024
#define SEQ 4096
#define BQ 64   // Kq
#define NB 16   // batch

typedef float f32x4 __attribute__((ext_vector_type(4)));
typedef __bf16 bf16x8 __attribute__((ext_vector_type(8)));

__device__ __forceinline__ void split_bf16(const float* x, bf16x8& hi, bf16x8& lo)
{
    #pragma unroll
    for (int i = 0; i < 8; ++i) {
        float v = x[i];
        __bf16 h = (__bf16)v;
        hi[i] = h;
        lo[i] = (__bf16)(v - (float)h);
    }
}

__device__ __forceinline__ void gload_lds16(const void* g, void* lds)
{
    __builtin_amdgcn_global_load_lds(
        (const __attribute__((address_space(1))) void*)g,
        (__attribute__((address_space(3))) void*)lds, 16, 0, 0);
}

// ---------------------------------------------------------------------------
// 512-thread split-K(x2)-in-block MFMA GEMM (BNK-true): C = A @ B^T*scale+bias
// CVEC: additionally cvec[m] += cscale * sum_n C[m][n]*bk[n] (atomic).
// ---------------------------------------------------------------------------
template<bool CVEC>
__global__ __launch_bounds__(512)
void gemm_bt_512(const float* __restrict__ A, const float* __restrict__ Bm,
                 const float* __restrict__ bias, float* __restrict__ C,
                 float scale, const float* __restrict__ bk,
                 float* __restrict__ cvec, float cscale)
{
    const int m0 = blockIdx.x * 64;
    const int n0 = blockIdx.y * 64;
    const int t   = threadIdx.x;
    const int w   = t >> 6;
    const int wm  = w & 3;      // m-subtile
    const int kh  = w >> 2;     // k-half
    const int l   = t & 63;
    const int row = l & 15;
    const int kg  = l >> 4;

    const float* ap = A + (size_t)(m0 + wm * 16 + row) * H + kh * 512 + kg * 8;
    const float* bp = Bm + (size_t)(n0 + row) * H + kh * 512 + kg * 8;

    f32x4 acc[4] = {};
    for (int k0 = 0; k0 < 512; k0 += 32) {
        float a8[8];
        *reinterpret_cast<float4*>(&a8[0]) = *reinterpret_cast<const float4*>(ap + k0);
        *reinterpret_cast<float4*>(&a8[4]) = *reinterpret_cast<const float4*>(ap + k0 + 4);
        bf16x8 ahi, alo;
        split_bf16(a8, ahi, alo);
        #pragma unroll
        for (int j = 0; j < 4; ++j) {
            float b8[8];
            const float* bjp = bp + (size_t)j * 16 * H + k0;
            *reinterpret_cast<float4*>(&b8[0]) = *reinterpret_cast<const float4*>(bjp);
            *reinterpret_cast<float4*>(&b8[4]) = *reinterpret_cast<const float4*>(bjp + 4);
            bf16x8 bhi, blo;
            split_bf16(b8, bhi, blo);
            acc[j] = __builtin_amdgcn_mfma_f32_16x16x32_bf16(ahi, bhi, acc[j], 0, 0, 0);
            acc[j] = __builtin_amdgcn_mfma_f32_16x16x32_bf16(ahi, blo, acc[j], 0, 0, 0);
            acc[j] = __builtin_amdgcn_mfma_f32_16x16x32_bf16(alo, bhi, acc[j], 0, 0, 0);
        }
    }

    __shared__ f32x4 red[4][4][64];   // partials from kh==1 waves (16 KB)
    if (kh == 1) {
        #pragma unroll
        for (int j = 0; j < 4; ++j) red[wm][j][l] = acc[j];
    }
    __syncthreads();
    if (kh == 0) {
        float p[4] = {0.f, 0.f, 0.f, 0.f};
        #pragma unroll
        for (int j = 0; j < 4; ++j) {
            f32x4 s = acc[j] + red[wm][j][l];
            int n = n0 + j * 16 + row;
            float bb = bias ? bias[n] : 0.f;
            float bkv = CVEC ? bk[n] : 0.f;
            #pragma unroll
            for (int r = 0; r < 4; ++r) {
                int m = m0 + wm * 16 + kg * 4 + r;
                float o = s[r] * scale + bb;
                C[(size_t)m * H + n] = o;
                if (CVEC) p[r] += o * bkv;
            }
        }
        if (CVEC) {
            #pragma unroll
            for (int r = 0; r < 4; ++r) {
                #pragma unroll
                for (int off = 1; off < 16; off <<= 1)
                    p[r] += __shfl_xor(p[r], off);
            }
            if (row == 0) {
                #pragma unroll
                for (int r = 0; r < 4; ++r)
                    atomicAdd(&cvec[m0 + wm * 16 + kg * 4 + r], p[r] * cscale);
            }
        }
    }
}

// ---------------------------------------------------------------------------
// N-proj, B read strided directly from Wk[k][n]: N = (q @ Wk) * scale
// -> pre-split bf16 hi/lo [m][n]. 512-thr split-K(x2).
// ---------------------------------------------------------------------------
__global__ __launch_bounds__(512)
void ngemm_direct(const float* __restrict__ A, const float* __restrict__ Wk,
                  __bf16* __restrict__ Nhi, __bf16* __restrict__ Nlo, float scale)
{
    const int m0 = blockIdx.x * 64;
    const int n0 = blockIdx.y * 64;
    const int t   = threadIdx.x;
    const int w   = t >> 6;
    const int wm  = w & 3;
    const int kh  = w >> 2;
    const int l   = t & 63;
    const int row = l & 15;
    const int kg  = l >> 4;

    const float* ap = A + (size_t)(m0 + wm * 16 + row) * H + kh * 512 + kg * 8;
    const float* bp = Wk + (size_t)(kh * 512 + kg * 8) * H + n0 + row;

    f32x4 acc[4] = {};
    for (int k0 = 0; k0 < 512; k0 += 32) {
        float a8[8];
        *reinterpret_cast<float4*>(&a8[0]) = *reinterpret_cast<const float4*>(ap + k0);
        *reinterpret_cast<float4*>(&a8[4]) = *reinterpret_cast<const float4*>(ap + k0 + 4);
        bf16x8 ahi, alo;
        split_bf16(a8, ahi, alo);
        #pragma unroll
        for (int j = 0; j < 4; ++j) {
            float b8[8];
            #pragma unroll
            for (int e = 0; e < 8; ++e)
                b8[e] = bp[(size_t)(k0 + e) * H + j * 16];
            bf16x8 bhi, blo;
            split_bf16(b8, bhi, blo);
            acc[j] = __builtin_amdgcn_mfma_f32_16x16x32_bf16(ahi, bhi, acc[j], 0, 0, 0);
            acc[j] = __builtin_amdgcn_mfma_f32_16x16x32_bf16(ahi, blo, acc[j], 0, 0, 0);
            acc[j] = __builtin_amdgcn_mfma_f32_16x16x32_bf16(alo, bhi, acc[j], 0, 0, 0);
        }
    }

    __shared__ f32x4 red[4][4][64];
    if (kh == 1) {
        #pragma unroll
        for (int j = 0; j < 4; ++j) red[wm][j][l] = acc[j];
    }
    __syncthreads();
    if (kh == 0) {
        #pragma unroll
        for (int j = 0; j < 4; ++j) {
            f32x4 s = acc[j] + red[wm][j][l];
            int n = n0 + j * 16 + row;
            #pragma unroll
            for (int r = 0; r < 4; ++r) {
                int m = m0 + wm * 16 + kg * 4 + r;
                float v = s[r] * scale;
                __bf16 hi = (__bf16)v;
                Nhi[(size_t)m * H + n] = hi;
                Nlo[(size_t)m * H + n] = (__bf16)(v - (float)hi);
            }
        }
    }
}

// ---------------------------------------------------------------------------
// scores[b,s,qi] = sum_h keys[b,s,h]*N[b,qi,h] + c[b,qi]   (R13 structure)
// ---------------------------------------------------------------------------
__global__ __launch_bounds__(512, 4)
void scores_mfma(const float* __restrict__ keys,
                 const __bf16* __restrict__ Nhi, const __bf16* __restrict__ Nlo,
                 const float* __restrict__ cvec, float* __restrict__ scores,
                 float* __restrict__ pmax, float* __restrict__ psum)
{
    const int id = blockIdx.x;          // 512 blocks
    const int x  = id & 7;
    const int m  = id >> 3;             // 0..63
    const int b  = 2 * x + (m >> 5);    // 2 batches per XCD
    const int ch = m & 31;
    const int s0 = ch * 128;

    const int t   = threadIdx.x;
    const int w   = t >> 6;             // 0..7
    const int l   = t & 63;
    const int row = l & 15;
    const int kg  = l >> 4;

    __shared__ __bf16 nshH[2][64][8][8];  // [buf][qi][slot][e] (16 KB)
    __shared__ __bf16 nshL[2][64][8][8];  // 16 KB
    __shared__ float redm[8][64];         // 2 KB

    const float* ka = keys + ((size_t)b * SEQ + s0 + w * 16 + row) * H + kg * 8;
    const __bf16* nhb = Nhi + (size_t)b * BQ * H;
    const __bf16* nlb = Nlo + (size_t)b * BQ * H;

    const int sqi = t >> 3;
    const int skb = t & 7;
    const int ssl = skb ^ (sqi & 7);

    float4 kr[2][4];
    bf16x8 nh[2], nl[2];
    #pragma unroll
    for (int ii = 0; ii < 2; ++ii) {
        kr[0][2 * ii + 0] = *reinterpret_cast<const float4*>(ka + ii * 32);
        kr[0][2 * ii + 1] = *reinterpret_cast<const float4*>(ka + ii * 32 + 4);
    }
    {
        size_t go = (size_t)sqi * H + skb * 8;
        nh[0] = *reinterpret_cast<const bf16x8*>(nhb + go);
        nl[0] = *reinterpret_cast<const bf16x8*>(nlb + go);
    }

    f32x4 acc[4] = {};
    #pragma unroll
    for (int c = 0; c < 16; ++c) {
        const int buf = c & 1;
        *reinterpret_cast<bf16x8*>(&nshH[buf][sqi][ssl][0]) = nh[buf];
        *reinterpret_cast<bf16x8*>(&nshL[buf][sqi][ssl][0]) = nl[buf];
        __syncthreads();
        if (c < 15) {
            const int kc = (c + 1) * 64;
            #pragma unroll
            for (int ii = 0; ii < 2; ++ii) {
                kr[buf ^ 1][2 * ii + 0] = *reinterpret_cast<const float4*>(ka + kc + ii * 32);
                kr[buf ^ 1][2 * ii + 1] = *reinterpret_cast<const float4*>(ka + kc + ii * 32 + 4);
            }
            size_t go = (size_t)sqi * H + kc + skb * 8;
            nh[buf ^ 1] = *reinterpret_cast<const bf16x8*>(nhb + go);
            nl[buf ^ 1] = *reinterpret_cast<const bf16x8*>(nlb + go);
        }
        #pragma unroll
        for (int ii = 0; ii < 2; ++ii) {
            float a8[8];
            *reinterpret_cast<float4*>(&a8[0]) = kr[buf][2 * ii + 0];
            *reinterpret_cast<float4*>(&a8[4]) = kr[buf][2 * ii + 1];
            bf16x8 ahi, alo;
            split_bf16(a8, ahi, alo);
            const int kb = ii * 4 + kg;
            const int slot = kb ^ (row & 7);
            #pragma unroll
            for (int j = 0; j < 4; ++j) {
                const int qi = j * 16 + row;
                bf16x8 bhi = *reinterpret_cast<const bf16x8*>(&nshH[buf][qi][slot][0]);
                bf16x8 blo = *reinterpret_cast<const bf16x8*>(&nshL[buf][qi][slot][0]);
                acc[j] = __builtin_amdgcn_mfma_f32_16x16x32_bf16(ahi, bhi, acc[j], 0, 0, 0);
                acc[j] = __builtin_amdgcn_mfma_f32_16x16x32_bf16(ahi, blo, acc[j], 0, 0, 0);
                acc[j] = __builtin_amdgcn_mfma_f32_16x16x32_bf16(alo, bhi, acc[j], 0, 0, 0);
            }
        }
    }

    #pragma unroll
    for (int j = 0; j < 4; ++j) {
        int qi = j * 16 + row;
        float cv = cvec[b * BQ + qi];
        #pragma unroll
        for (int r = 0; r < 4; ++r) {
            acc[j][r] += cv;
            int s = s0 + w * 16 + kg * 4 + r;
            scores[((size_t)b * SEQ + s) * BQ + qi] = acc[j][r];
        }
    }
    float mj[4];
    #pragma unroll
    for (int j = 0; j < 4; ++j) {
        float mm = fmaxf(fmaxf(acc[j][0], acc[j][1]), fmaxf(acc[j][2], acc[j][3]));
        mm = fmaxf(mm, __shfl_xor(mm, 16));
        mm = fmaxf(mm, __shfl_xor(mm, 32));
        mj[j] = mm;
    }
    __syncthreads();
    if (kg == 0) {
        #pragma unroll
        for (int j = 0; j < 4; ++j) redm[w][j * 16 + row] = mj[j];
    }
    __syncthreads();
    float Mj[4];
    #pragma unroll
    for (int j = 0; j < 4; ++j) {
        const int qi = j * 16 + row;
        float M = redm[0][qi];
        #pragma unroll
        for (int ww = 1; ww < 8; ++ww) M = fmaxf(M, redm[ww][qi]);
        Mj[j] = M;
    }
    float sj[4];
    #pragma unroll
    for (int j = 0; j < 4; ++j) {
        float s = 0.f;
        #pragma unroll
        for (int r = 0; r < 4; ++r) s += __expf(acc[j][r] - Mj[j]);
        s += __shfl_xor(s, 16);
        s += __shfl_xor(s, 32);
        sj[j] = s;
    }
    __syncthreads();
    if (kg == 0) {
        #pragma unroll
        for (int j = 0; j < 4; ++j) redm[w][j * 16 + row] = sj[j];
    }
    __syncthreads();
    if (w == 0 && kg == 0) {
        #pragma unroll
        for (int j = 0; j < 4; ++j) {
            const int qi = j * 16 + row;
            float ss = 0.f;
            #pragma unroll
            for (int ww = 0; ww < 8; ++ww) ss += redm[ww][qi];
            pmax[((size_t)b * 32 + ch) * 64 + qi] = Mj[j];
            psum[((size_t)b * 32 + ch) * 64 + qi] = ss;
        }
    }
}

// ---------------------------------------------------------------------------
// normalize in place (inline global-stat combine) + bf16 transposed copy
// ---------------------------------------------------------------------------
__global__ __launch_bounds__(256)
void sm_norm(float* __restrict__ attn, const float* __restrict__ pmax,
             const float* __restrict__ psum, __hip_bfloat16* __restrict__ abfT)
{
    __shared__ float tile[64][133];
    const int b  = blockIdx.y;
    const int ch = blockIdx.x;
    const int t  = threadIdx.x;
    const int qi = t & 63;
    const int g  = t >> 6;

    float M = -1e30f;
    #pragma unroll 4
    for (int c = 0; c < 32; ++c)
        M = fmaxf(M, pmax[((size_t)b * 32 + c) * 64 + qi]);
    float ssum = 0.f;
    #pragma unroll 4
    for (int c = 0; c < 32; ++c)
        ssum += psum[((size_t)b * 32 + c) * 64 + qi] *
                __expf(pmax[((size_t)b * 32 + c) * 64 + qi] - M);
    const float inv = 1.f / ssum;

    float* sb = attn + ((size_t)b * SEQ + ch * 128) * BQ;
    #pragma unroll 8
    for (int i = 0; i < 32; ++i) {
        int sl = g + i * 4;
        size_t idx = (size_t)sl * BQ + qi;
        float w = __expf(sb[idx] - M) * inv;
        sb[idx] = w;
        tile[qi][sl] = w;
    }
    __syncthreads();
    const int qo = t >> 2;
    const int c  = (t & 3) * 32;
    __hip_bfloat16* dst = abfT + ((size_t)(b * BQ + qo)) * SEQ + ch * 128 + c;
    #pragma unroll
    for (int v = 0; v < 4; ++v) {
        bf16x8 w8;
        #pragma unroll
        for (int e = 0; e < 8; ++e)
            w8[e] = (__bf16)tile[qo][c + v * 8 + e];
        *reinterpret_cast<bf16x8*>(dst + v * 8) = w8;
    }
}

// ---------------------------------------------------------------------------
// Tpart[sc][b][qi][h] = sum_{s in chunk} abfT[b,qi,s] * values[b,s,h]
// ALL operands staged via global_load_lds; 3-buffer pipeline staged 2 tiles
// ahead; counted s_waitcnt vmcnt(N) + raw s_barrier — T3/T4. T5: s_setprio
// around the MFMA cluster (phase-split schedule -> arbitration pays).
// ---------------------------------------------------------------------------
template<int SC>
__global__ __launch_bounds__(256)
void tmat_mfma(const __hip_bfloat16* __restrict__ abfT,
               const float* __restrict__ values,
               float* __restrict__ Tpart)
{
    constexpr int schunk = SEQ / SC;
    constexpr int nk = schunk / 32;

    const int i  = blockIdx.x;
    const int h0 = ((i >> 3) & 7) * 128;
    const int g  = (i & 7) + 8 * (i >> 6);
    const int b  = g / SC;
    const int sc = g % SC;

    const int w   = threadIdx.x >> 6;
    const int l   = threadIdx.x & 63;
    const int row = l & 15;
    const int kg  = l >> 4;
    const int sbase = sc * schunk;

    __shared__ float vlds[3][32][128];            // 48 KB
    __shared__ __hip_bfloat16 alds[3][64][32];    // 12 KB

    const __hip_bfloat16* ab = abfT + (size_t)b * BQ * SEQ + sbase;
    const float* vb = values + ((size_t)b * SEQ + sbase) * H + h0;

    #define VSTAGE(buf, c)                                                     \
        {                                                                      \
            _Pragma("unroll")                                                  \
            for (int ii = 0; ii < 4; ++ii) {                                   \
                int elem = w * 1024 + ii * 256 + l * 4;                        \
                int k    = elem >> 7;                                          \
                int cc   = elem & 127;                                         \
                int csw  = cc ^ ((k >> 3) << 4);                               \
                const float* src = vb + (size_t)((c) * 32 + k) * H + csw;      \
                gload_lds16(src, (void*)(&vlds[buf][0][0] + w * 1024 + ii * 256)); \
            }                                                                  \
        }
    #define ASTAGE(buf, c)                                                     \
        {                                                                      \
            int aqi = w * 16 + (l >> 2);                                       \
            const __hip_bfloat16* srcA =                                       \
                ab + (size_t)aqi * SEQ + (c) * 32 + (l & 3) * 8;               \
            gload_lds16(srcA, (void*)(&alds[buf][0][0] + w * 512));            \
        }

    f32x4 acc[4][2] = {};
    ASTAGE(0, 0); VSTAGE(0, 0);
    ASTAGE(1, 1); VSTAGE(1, 1);

    for (int ks = 0; ks < nk; ++ks) {
        const int buf = ks % 3;
        if (ks + 2 < nk) {
            const int nb2 = (ks + 2) % 3;
            ASTAGE(nb2, ks + 2); VSTAGE(nb2, ks + 2);
            asm volatile("s_waitcnt vmcnt(10)" ::: "memory");
        } else if (ks + 1 < nk) {
            asm volatile("s_waitcnt vmcnt(5)" ::: "memory");
        } else {
            asm volatile("s_waitcnt vmcnt(0)" ::: "memory");
        }
        __builtin_amdgcn_sched_barrier(0);
        __builtin_amdgcn_s_barrier();      // tile ks visible to all waves
        __builtin_amdgcn_sched_barrier(0);

        // compute tile ks from LDS (T5: boost priority for the MFMA cluster)
        __builtin_amdgcn_s_setprio(1);
        bf16x8 a[4];
        #pragma unroll
        for (int q = 0; q < 4; ++q)
            a[q] = *reinterpret_cast<const bf16x8*>(&alds[buf][q * 16 + row][kg * 8]);
        #pragma unroll
        for (int j = 0; j < 2; ++j) {
            const int col = (w * 32 + j * 16 + row) ^ (kg << 4);
            float b8[8];
            #pragma unroll
            for (int e = 0; e < 8; ++e)
                b8[e] = vlds[buf][kg * 8 + e][col];
            bf16x8 bhi, blo;
            split_bf16(b8, bhi, blo);
            #pragma unroll
            for (int q = 0; q < 4; ++q) {
                acc[q][j] = __builtin_amdgcn_mfma_f32_16x16x32_bf16(a[q], bhi, acc[q][j], 0, 0, 0);
                acc[q][j] = __builtin_amdgcn_mfma_f32_16x16x32_bf16(a[q], blo, acc[q][j], 0, 0, 0);
            }
        }
        __builtin_amdgcn_s_setprio(0);
        __builtin_amdgcn_sched_barrier(0);
        __builtin_amdgcn_s_barrier();      // compute(ks) done everywhere ->
        __builtin_amdgcn_sched_barrier(0); // buf may be overwritten next iter
    }
    #undef VSTAGE
    #undef ASTAGE

    float* tp = Tpart + ((size_t)sc * NB + b) * BQ * H;
    #pragma unroll
    for (int q = 0; q < 4; ++q) {
        #pragma unroll
        for (int j = 0; j < 2; ++j) {
            int h = h0 + w * 32 + j * 16 + row;
            #pragma unroll
            for (int r = 0; r < 4; ++r) {
                int qi = q * 16 + kg * 4 + r;
                tp[(size_t)qi * H + h] = acc[q][j][r];
            }
        }
    }
}

// ---------------------------------------------------------------------------
// In-place partial reduction: Tpart[0][i] = sum_p Tpart[p][i]
// ---------------------------------------------------------------------------
template<int SC>
__global__ __launch_bounds__(256)
void tsum_kernel(float* __restrict__ Tpart)
{
    const size_t stride = (size_t)NB * BQ * H;
    size_t i = ((size_t)blockIdx.x * 256 + threadIdx.x) * 4;
    f32x4 s = *reinterpret_cast<const f32x4*>(Tpart + i);
    #pragma unroll
    for (int p = 1; p < SC; ++p)
        s += *reinterpret_cast<const f32x4*>(Tpart + p * stride + i);
    *reinterpret_cast<f32x4*>(Tpart + i) = s;
}

// ---------------------------------------------------------------------------
extern "C" void kernel_launch(void* const* d_in, const int* in_sizes, int n_in,
                              void* d_out, int out_size, void* d_ws, size_t ws_size,
                              hipStream_t stream)
{
    const float* queries = (const float*)d_in[0];
    const float* keys    = (const float*)d_in[1];
    const float* values  = (const float*)d_in[2];
    const float* Wq = (const float*)d_in[3];
    const float* bq = (const float*)d_in[4];
    const float* Wk = (const float*)d_in[5];
    const float* bk = (const float*)d_in[6];
    const float* Wv = (const float*)d_in[7];
    const float* bv = (const float*)d_in[8];

    float* out     = (float*)d_out;
    float* context = out;                          // 16*64*1024 f32
    float* attn    = out + (size_t)NB * BQ * H;    // 16*4096*64 f32

    const int SC = (ws_size >= (41ull << 20)) ? 8 : 2;

    char* ws = (char*)d_ws;
    float* q     = (float*)ws;                              // 4 MB  [0,4)
    __bf16* Nhi  = (__bf16*)(ws + (8ull << 20));            // 2 MB  [8,10)
    __bf16* Nlo  = (__bf16*)(ws + (10ull << 20));           // 2 MB  [10,12)
    float* Tpart = (float*)ws;                              // SC*4 MB (overlaps q/N, dead by tmat)
    __hip_bfloat16* abfT = (__hip_bfloat16*)(ws + (size_t)SC * (4ull << 20)); // 8 MB
    char* smalls = ws + (size_t)SC * (4ull << 20) + (8ull << 20);
    float* cvec  = (float*)smalls;                          // 4 KB
    float* pmax  = (float*)(smalls + (128u << 10));         // 128 KB
    float* psum  = (float*)(smalls + (512u << 10));         // 128 KB

    const float scale = 0.03125f; // 1/sqrt(1024)

    // cvec accumulated atomically in q-GEMM epilogue
    hipMemsetAsync(cvec, 0, (size_t)NB * BQ * sizeof(float), stream);
    // q = queries @ Wq^T + bq  (+ cvec = scale*(q . bk))
    gemm_bt_512<true><<<dim3(16, 16), 512, 0, stream>>>(
        queries, Wq, bq, q, 1.0f, bk, cvec, scale);
    // N = (q @ Wk) * scale -> pre-split bf16 hi/lo (Wk read strided, no transpose)
    ngemm_direct<<<dim3(16, 16), 512, 0, stream>>>(q, Wk, Nhi, Nlo, scale);
    // scores + fused per-chunk softmax stats
    scores_mfma<<<512, 512, 0, stream>>>(keys, Nhi, Nlo, cvec, attn, pmax, psum);
    // normalize (inline stat combine) + bf16 transposed copy
    sm_norm<<<dim3(32, NB), 256, 0, stream>>>(attn, pmax, psum, abfT);
    // T partials = attn^T @ values (counted-vmcnt 3-buffer pipeline + setprio)
    if (SC == 8) tmat_mfma<8><<<8 * NB * 8, 256, 0, stream>>>(abfT, values, Tpart);
    else         tmat_mfma<2><<<8 * NB * 2, 256, 0, stream>>>(abfT, values, Tpart);
    // Tsum (in place into partial 0)
    if (SC == 8) tsum_kernel<8><<<1024, 256, 0, stream>>>(Tpart);
    else         tsum_kernel<2><<<1024, 256, 0, stream>>>(Tpart);
    // context = Tsum @ Wv^T + bv
    gemm_bt_512<false><<<dim3(16, 16), 512, 0, stream>>>(
        Tpart, Wv, bv, context, 1.0f, nullptr, nullptr, 0.f);
}